// Round 1
// baseline (3432.690 us; speedup 1.0000x reference)
//
#include <hip/hip_runtime.h>
#include <math.h>

// Problem constants
// B=8, C=256, H=32, W=32, L=1024, HEADS=4 (dh=64), IC=64,
// D_INNER=512, DT_RANK=16, D_STATE=16, D_CONV=4, DEPTH=2, M=B*L=8192

// ---------------------------------------------------------------------------
// Batched transpose: in (Bn, R, S) -> out (Bn, S, R)
// ---------------------------------------------------------------------------
__global__ __launch_bounds__(256)
void transpose_kernel(const float* __restrict__ in, float* __restrict__ out,
                      int R, int S)
{
    __shared__ float tile[32][33];
    int b  = blockIdx.z;
    int s0 = blockIdx.x * 32, r0 = blockIdx.y * 32;
    const float* inb = in + (size_t)b * R * S;
    float* outb = out + (size_t)b * R * S;
    int tx = threadIdx.x, ty = threadIdx.y;  // 32 x 8
    #pragma unroll
    for (int j = 0; j < 32; j += 8)
        tile[ty + j][tx] = inb[(size_t)(r0 + ty + j) * S + (s0 + tx)];
    __syncthreads();
    #pragma unroll
    for (int j = 0; j < 32; j += 8)
        outb[(size_t)(s0 + ty + j) * R + (r0 + tx)] = tile[tx][ty + j];
}

// ---------------------------------------------------------------------------
// Generic linear: Cout[M,N] = act(A[M,K](lda) @ W[N,K]^T + bias)
// act: 0 = none, 1 = softplus
// BM=128 fixed, BN in {128,64}, 16x16 threads, micro-tile 8 x TN
// Requires: M % 128 == 0, K % 16 == 0, lda % 4 == 0
// ---------------------------------------------------------------------------
template <int BN, int TN>
__global__ __launch_bounds__(256)
void linear_kernel(const float* __restrict__ A, int lda,
                   const float* __restrict__ W, const float* __restrict__ bias,
                   float* __restrict__ Cout,
                   int M, int N, int K, int act)
{
    constexpr int BM = 128;
    __shared__ __align__(16) float As[16][BM + 4];
    __shared__ __align__(16) float Ws[16][BN + 4];
    int tid = threadIdx.x;
    int tx = tid & 15, ty = tid >> 4;
    int m0 = blockIdx.y * BM, n0 = blockIdx.x * BN;

    float acc[8][TN];
    #pragma unroll
    for (int i = 0; i < 8; ++i)
        #pragma unroll
        for (int j = 0; j < TN; ++j) acc[i][j] = 0.f;

    for (int k0 = 0; k0 < K; k0 += 16) {
        for (int t = tid; t < 4 * BM; t += 256) {
            int r = t >> 2, kk = (t & 3) << 2;
            float4 v = *(const float4*)(A + (size_t)(m0 + r) * lda + (k0 + kk));
            As[kk + 0][r] = v.x; As[kk + 1][r] = v.y;
            As[kk + 2][r] = v.z; As[kk + 3][r] = v.w;
        }
        for (int t = tid; t < 4 * BN; t += 256) {
            int r = t >> 2, kk = (t & 3) << 2;
            float4 v = make_float4(0.f, 0.f, 0.f, 0.f);
            if (n0 + r < N)
                v = *(const float4*)(W + (size_t)(n0 + r) * K + (k0 + kk));
            Ws[kk + 0][r] = v.x; Ws[kk + 1][r] = v.y;
            Ws[kk + 2][r] = v.z; Ws[kk + 3][r] = v.w;
        }
        __syncthreads();
        #pragma unroll
        for (int kk = 0; kk < 16; ++kk) {
            float a[8], bb[TN];
            *(float4*)&a[0] = *(const float4*)&As[kk][ty * 8 + 0];
            *(float4*)&a[4] = *(const float4*)&As[kk][ty * 8 + 4];
            #pragma unroll
            for (int j = 0; j < TN; j += 4)
                *(float4*)&bb[j] = *(const float4*)&Ws[kk][tx * TN + j];
            #pragma unroll
            for (int i = 0; i < 8; ++i)
                #pragma unroll
                for (int j = 0; j < TN; ++j)
                    acc[i][j] += a[i] * bb[j];
        }
        __syncthreads();
    }

    #pragma unroll
    for (int i = 0; i < 8; ++i) {
        int m = m0 + ty * 8 + i;
        #pragma unroll
        for (int j = 0; j < TN; ++j) {
            int n = n0 + tx * TN + j;
            if (n < N) {
                float v = acc[i][j];
                if (bias) v += bias[n];
                if (act == 1) v = (v > 30.f) ? v : log1pf(expf(v));
                Cout[(size_t)m * N + n] = v;
            }
        }
    }
}

// ---------------------------------------------------------------------------
// Cross-attention core (per b, head, 8-query tile): softmax(QK^T/8) V
// Q,K,V,O in (B,L,C) layout, head h occupies columns h*64..h*64+63
// ---------------------------------------------------------------------------
__global__ __launch_bounds__(256)
void attn_kernel(const float* __restrict__ Q, const float* __restrict__ K,
                 const float* __restrict__ V, float* __restrict__ O)
{
    __shared__ __align__(16) float qs[8][68];
    __shared__ __align__(16) float sc[8][1025];
    int blk = blockIdx.x;           // 4096 = 8 * 4 * 128
    int qt = blk & 127;
    int h  = (blk >> 7) & 3;
    int b  = blk >> 9;
    int tid = threadIdx.x;
    int q0 = qt * 8;
    size_t rowbase = (size_t)b * 1024;

    for (int i = tid; i < 512; i += 256) {
        int r = i >> 6, d = i & 63;
        qs[r][d] = Q[(rowbase + q0 + r) * 256 + h * 64 + d];
    }
    __syncthreads();

    // scores
    for (int i = tid; i < 8192; i += 256) {
        int r = i & 7, kc = i >> 3;
        const float4* kp = (const float4*)(K + (rowbase + kc) * 256 + h * 64);
        const float4* qp = (const float4*)(&qs[r][0]);
        float s = 0.f;
        #pragma unroll
        for (int dd = 0; dd < 16; ++dd) {
            float4 kv = kp[dd];
            float4 qv = qp[dd];
            s += kv.x * qv.x + kv.y * qv.y + kv.z * qv.z + kv.w * qv.w;
        }
        sc[r][kc] = s * 0.125f;
    }
    __syncthreads();

    // softmax per row (32 lanes per row)
    {
        int r = tid >> 5, sub = tid & 31;
        float mx = -3.0e38f;
        for (int kc = sub; kc < 1024; kc += 32) mx = fmaxf(mx, sc[r][kc]);
        #pragma unroll
        for (int m = 16; m >= 1; m >>= 1) mx = fmaxf(mx, __shfl_xor(mx, m));
        float sum = 0.f;
        for (int kc = sub; kc < 1024; kc += 32) {
            float e = expf(sc[r][kc] - mx);
            sc[r][kc] = e;
            sum += e;
        }
        #pragma unroll
        for (int m = 16; m >= 1; m >>= 1) sum += __shfl_xor(sum, m);
        float inv = 1.f / sum;
        for (int kc = sub; kc < 1024; kc += 32) sc[r][kc] *= inv;
    }
    __syncthreads();

    // PV
    {
        int d = tid & 63, r0 = tid >> 6;  // rows r0 and r0+4
        const float* vp = V + rowbase * 256 + h * 64 + d;
        float a0 = 0.f, a1 = 0.f;
        for (int kc = 0; kc < 1024; ++kc) {
            float vv = vp[(size_t)kc * 256];
            a0 += sc[r0][kc] * vv;
            a1 += sc[r0 + 4][kc] * vv;
        }
        O[(rowbase + q0 + r0) * 256 + h * 64 + d] = a0;
        O[(rowbase + q0 + r0 + 4) * 256 + h * 64 + d] = a1;
    }
}

// ---------------------------------------------------------------------------
// Criss-cross attention, one block per (b, line, branch).
// horizontal (vert=0): line = image row, stride 1 over W
// vertical   (vert=1): line = image col, stride 32 over H
// QC,KC: (B,L,64); VC: (B,L,256)
// ---------------------------------------------------------------------------
__global__ __launch_bounds__(256)
void cca_kernel(const float* __restrict__ QC, const float* __restrict__ KC,
                const float* __restrict__ VC,
                float* __restrict__ OH, float* __restrict__ OV)
{
    int rowid = blockIdx.x;       // 0..31
    int b     = blockIdx.y;
    int vert  = blockIdx.z;
    int base   = vert ? rowid : rowid * 32;
    int stride = vert ? 32 : 1;
    size_t pix0 = (size_t)b * 1024 + base;

    __shared__ float qs[32][65];
    __shared__ float ks[32][65];
    __shared__ float ps[32][33];

    int tid = threadIdx.x;
    for (int i = tid; i < 2048; i += 256) {
        int w = i >> 6, c = i & 63;
        size_t p = pix0 + (size_t)w * stride;
        qs[w][c] = QC[p * 64 + c];
        ks[w][c] = KC[p * 64 + c];
    }
    __syncthreads();

    // scores + softmax (no scale factor, matching reference)
    {
        int wp = tid & 31, wr = tid >> 5;
        #pragma unroll
        for (int g = 0; g < 4; ++g) {
            int w = wr + g * 8;
            float s = 0.f;
            #pragma unroll
            for (int c = 0; c < 64; ++c) s += qs[w][c] * ks[wp][c];
            float mx = s;
            #pragma unroll
            for (int m = 16; m >= 1; m >>= 1) mx = fmaxf(mx, __shfl_xor(mx, m));
            float e = expf(s - mx);
            float sum = e;
            #pragma unroll
            for (int m = 16; m >= 1; m >>= 1) sum += __shfl_xor(sum, m);
            ps[w][wp] = e / sum;
        }
    }
    __syncthreads();

    // PV: one channel per thread, 32 output positions
    {
        int c = tid;
        float acc[32];
        #pragma unroll
        for (int w = 0; w < 32; ++w) acc[w] = 0.f;
        for (int wp = 0; wp < 32; ++wp) {
            float vv = VC[(pix0 + (size_t)wp * stride) * 256 + c];
            #pragma unroll
            for (int w = 0; w < 32; ++w) acc[w] += ps[w][wp] * vv;
        }
        float* Oo = vert ? OV : OH;
        for (int w = 0; w < 32; ++w)
            Oo[(pix0 + (size_t)w * stride) * 256 + c] = acc[w];
    }
}

// Out = gamma*(OH+OV) + X
__global__ __launch_bounds__(256)
void combine_kernel(const float* __restrict__ OH, const float* __restrict__ OV,
                    const float* __restrict__ X, const float* __restrict__ gamma,
                    float* __restrict__ Out)
{
    int idx = blockIdx.x * 256 + threadIdx.x;
    float g = gamma[0];
    Out[idx] = g * (OH[idx] + OV[idx]) + X[idx];
}

// ---------------------------------------------------------------------------
// Causal depthwise conv(4) + bias + silu.  XZ: (B,L,1024), u = cols 0..511.
// U out: (B,L,512)
// ---------------------------------------------------------------------------
__global__ __launch_bounds__(256)
void conv_silu_kernel(const float* __restrict__ XZ, const float* __restrict__ cw,
                      const float* __restrict__ cb, float* __restrict__ U)
{
    int idx = blockIdx.x * 256 + threadIdx.x;   // B*L*512 = 4194304
    int d = idx & 511;
    int l = (idx >> 9) & 1023;
    int b = idx >> 19;
    float acc = cb[d];
    #pragma unroll
    for (int j = 0; j < 4; ++j) {
        int ls = l - 3 + j;
        if (ls >= 0)
            acc += XZ[((size_t)(b * 1024 + ls)) * 1024 + d] * cw[d * 4 + j];
    }
    U[idx] = acc / (1.f + expf(-acc));   // silu
}

// ---------------------------------------------------------------------------
// Selective scan. One lane per (b,d,n): n = lane&15.
// h_t = exp(delta*A)*h + delta*Bm*u ; y_t = sum_n h*Cm  (shfl reduce)
// epilogue fused: out = (y + u*Dp) * silu(z); written into XZ cols 0..511
// ---------------------------------------------------------------------------
__global__ __launch_bounds__(256)
void scan_kernel(const float* __restrict__ DL, const float* __restrict__ U,
                 const float* __restrict__ XD, float* __restrict__ XZ,
                 const float* __restrict__ A_log, const float* __restrict__ Dp)
{
    int idx = blockIdx.x * 256 + threadIdx.x;  // 65536 = 8*512*16
    int n = idx & 15;
    int d = (idx >> 4) & 511;
    int b = idx >> 13;

    float Acoef = -expf(A_log[d * 16 + n]);
    float Dval  = Dp[d];
    float h = 0.f;

    const float* dl = DL + (size_t)b * 1024 * 512 + d;
    const float* uu = U  + (size_t)b * 1024 * 512 + d;
    const float* xd = XD + (size_t)b * 1024 * 48;
    float* xz = XZ + (size_t)b * 1024 * 1024;

    for (int t = 0; t < 1024; ++t) {
        float delta = dl[(size_t)t * 512];
        float u     = uu[(size_t)t * 512];
        float Bm    = xd[t * 48 + 16 + n];
        float Cm    = xd[t * 48 + 32 + n];
        float dA = expf(delta * Acoef);
        h = dA * h + (delta * u) * Bm;
        float y = h * Cm;
        y += __shfl_xor(y, 1);
        y += __shfl_xor(y, 2);
        y += __shfl_xor(y, 4);
        y += __shfl_xor(y, 8);
        if (n == 0) {
            float z = xz[(size_t)t * 1024 + 512 + d];
            float out = (y + u * Dval) * (z / (1.f + expf(-z)));
            xz[(size_t)t * 1024 + d] = out;   // Y reuses dead u-half of XZ
        }
    }
}

// ---------------------------------------------------------------------------
extern "C" void kernel_launch(void* const* d_in, const int* in_sizes, int n_in,
                              void* d_out, int out_size, void* d_ws, size_t ws_size,
                              hipStream_t stream)
{
    (void)in_sizes; (void)n_in; (void)out_size; (void)ws_size;
    const float* sam   = (const float*)d_in[0];
    const float* myn   = (const float*)d_in[1];
    const float* wq    = (const float*)d_in[2];
    const float* bq    = (const float*)d_in[3];
    const float* wk    = (const float*)d_in[4];
    const float* bk    = (const float*)d_in[5];
    const float* wv    = (const float*)d_in[6];
    const float* bv    = (const float*)d_in[7];
    const float* wo    = (const float*)d_in[8];
    const float* bo    = (const float*)d_in[9];
    const float* cqw   = (const float*)d_in[10];
    const float* cqb   = (const float*)d_in[11];
    const float* ckw   = (const float*)d_in[12];
    const float* ckb   = (const float*)d_in[13];
    const float* cvw   = (const float*)d_in[14];
    const float* cvb   = (const float*)d_in[15];
    const float* gamma = (const float*)d_in[16];
    const float* to_seq_w   = (const float*)d_in[17];
    const float* to_seq_b   = (const float*)d_in[18];
    const float* in_proj_w  = (const float*)d_in[19];
    const float* conv_w     = (const float*)d_in[20];
    const float* conv_b     = (const float*)d_in[21];
    const float* x_proj_w   = (const float*)d_in[22];
    const float* dt_w       = (const float*)d_in[23];
    const float* dt_b       = (const float*)d_in[24];
    const float* A_log      = (const float*)d_in[25];
    const float* Dp         = (const float*)d_in[26];
    const float* out_proj_w = (const float*)d_in[27];
    const float* from_seq_w = (const float*)d_in[28];
    const float* from_seq_b = (const float*)d_in[29];

    // workspace layout (floats); total 21,364,736 floats ~= 85.5 MB
    float* ws = (float*)d_ws;
    float* P0 = ws;                         // (B,L,C)  2097152
    float* P1 = ws + (size_t)2097152;       // (B,L,C)  2097152
    float* W0 = ws + (size_t)4194304;       // 8388608  (Q/K/V/O, then XZ)
    float* W1 = ws + (size_t)12582912;      // 4194304  (qc/kc/vc, then U)
    float* W2 = ws + (size_t)16777216;      // 4194304  (OH/OV, T, DL, MO)
    float* W4 = ws + (size_t)20971520;      // 393216   (XD)

    dim3 tb(32, 8, 1);
    // inputs (B,C,L) -> (B,L,C)
    transpose_kernel<<<dim3(32, 8, 8), tb, 0, stream>>>(sam, P0, 256, 1024);
    transpose_kernel<<<dim3(32, 8, 8), tb, 0, stream>>>(myn, P1, 256, 1024);

    auto lin128 = [&](const float* A, int lda, const float* Wp, const float* bias,
                      float* Cout, int N, int K, int act) {
        linear_kernel<128, 8><<<dim3((N + 127) / 128, 64), 256, 0, stream>>>(
            A, lda, Wp, bias, Cout, 8192, N, K, act);
    };
    auto lin64 = [&](const float* A, int lda, const float* Wp, const float* bias,
                     float* Cout, int N, int K, int act) {
        linear_kernel<64, 4><<<dim3((N + 63) / 64, 64), 256, 0, stream>>>(
            A, lda, Wp, bias, Cout, 8192, N, K, act);
    };

    // ---- cross attention ----
    float* Qb = W0;
    float* Kb = W0 + 2097152;
    float* Vb = W0 + 4194304;
    float* Ob = W0 + 6291456;
    lin128(P0, 256, wq, bq, Qb, 256, 256, 0);
    lin128(P1, 256, wk, bk, Kb, 256, 256, 0);
    lin128(P1, 256, wv, bv, Vb, 256, 256, 0);
    attn_kernel<<<4096, 256, 0, stream>>>(Qb, Kb, Vb, Ob);
    lin128(Ob, 256, wo, bo, P0, 256, 256, 0);      // fusion -> P0

    // ---- criss-cross attention ----
    float* QC = W1;
    float* KC = W1 + 524288;
    float* VC = W1 + 1048576;
    lin64 (P0, 256, cqw, cqb, QC, 64, 256, 0);
    lin64 (P0, 256, ckw, ckb, KC, 64, 256, 0);
    lin128(P0, 256, cvw, cvb, VC, 256, 256, 0);
    float* OH = W2;
    float* OV = W2 + 2097152;
    cca_kernel<<<dim3(32, 8, 2), 256, 0, stream>>>(QC, KC, VC, OH, OV);
    combine_kernel<<<8192, 256, 0, stream>>>(OH, OV, P0, gamma, P1); // spatial -> P1

    // ---- 2x mamba blocks ----
    for (int i = 0; i < 2; ++i) {
        const float* Sin = (i == 0) ? P1 : P0;
        float* Sout      = (i == 0) ? P0 : P1;
        float* T = W2;
        lin128(Sin, 256, to_seq_w + (size_t)i * 65536, to_seq_b + i * 256, T, 256, 256, 0);
        lin128(T, 256, in_proj_w + (size_t)i * 262144, nullptr, W0, 1024, 256, 0); // XZ
        conv_silu_kernel<<<16384, 256, 0, stream>>>(W0, conv_w + (size_t)i * 2048,
                                                    conv_b + i * 512, W1);         // U
        lin64 (W1, 512, x_proj_w + (size_t)i * 24576, nullptr, W4, 48, 512, 0);    // XD
        lin128(W4, 48, dt_w + (size_t)i * 8192, dt_b + i * 512, W2, 512, 16, 1);   // DL (softplus)
        scan_kernel<<<256, 256, 0, stream>>>(W2, W1, W4, W0,
                                             A_log + (size_t)i * 8192, Dp + i * 512);
        lin128(W0, 1024, out_proj_w + (size_t)i * 131072, nullptr, W2, 256, 512, 0); // MO
        lin128(W2, 256, from_seq_w + (size_t)i * 65536, from_seq_b + i * 256, Sout, 256, 256, 0);
    }

    // final (B,L,C) -> (B,C,L)
    transpose_kernel<<<dim3(8, 32, 8), tb, 0, stream>>>(P1, (float*)d_out, 1024, 256);
}

// Round 2
// 2074.058 us; speedup vs baseline: 1.6551x; 1.6551x over previous
//
#include <hip/hip_runtime.h>
#include <math.h>

// Problem constants
// B=8, C=256, H=32, W=32, L=1024, HEADS=4 (dh=64), IC=64,
// D_INNER=512, DT_RANK=16, D_STATE=16, D_CONV=4, DEPTH=2, M=B*L=8192

// ---------------------------------------------------------------------------
// Batched transpose: in (Bn, R, S) -> out (Bn, S, R)
// ---------------------------------------------------------------------------
__global__ __launch_bounds__(256)
void transpose_kernel(const float* __restrict__ in, float* __restrict__ out,
                      int R, int S)
{
    __shared__ float tile[32][33];
    int b  = blockIdx.z;
    int s0 = blockIdx.x * 32, r0 = blockIdx.y * 32;
    const float* inb = in + (size_t)b * R * S;
    float* outb = out + (size_t)b * R * S;
    int tx = threadIdx.x, ty = threadIdx.y;  // 32 x 8
    #pragma unroll
    for (int j = 0; j < 32; j += 8)
        tile[ty + j][tx] = inb[(size_t)(r0 + ty + j) * S + (s0 + tx)];
    __syncthreads();
    #pragma unroll
    for (int j = 0; j < 32; j += 8)
        outb[(size_t)(s0 + ty + j) * R + (r0 + tx)] = tile[tx][ty + j];
}

// ---------------------------------------------------------------------------
// Generic linear: Cout[M,N] = act(A[M,K](lda) @ W[N,K]^T + bias)
// act: 0 = none, 1 = softplus
// BM=128 fixed, BN in {128,64}, 16x16 threads, micro-tile 8 x TN
// Requires: M % 128 == 0, K % 16 == 0, lda % 4 == 0
// ---------------------------------------------------------------------------
template <int BN, int TN>
__global__ __launch_bounds__(256)
void linear_kernel(const float* __restrict__ A, int lda,
                   const float* __restrict__ W, const float* __restrict__ bias,
                   float* __restrict__ Cout,
                   int M, int N, int K, int act)
{
    constexpr int BM = 128;
    __shared__ __align__(16) float As[16][BM + 4];
    __shared__ __align__(16) float Ws[16][BN + 4];
    int tid = threadIdx.x;
    int tx = tid & 15, ty = tid >> 4;
    int m0 = blockIdx.y * BM, n0 = blockIdx.x * BN;

    float acc[8][TN];
    #pragma unroll
    for (int i = 0; i < 8; ++i)
        #pragma unroll
        for (int j = 0; j < TN; ++j) acc[i][j] = 0.f;

    for (int k0 = 0; k0 < K; k0 += 16) {
        for (int t = tid; t < 4 * BM; t += 256) {
            int r = t >> 2, kk = (t & 3) << 2;
            float4 v = *(const float4*)(A + (size_t)(m0 + r) * lda + (k0 + kk));
            As[kk + 0][r] = v.x; As[kk + 1][r] = v.y;
            As[kk + 2][r] = v.z; As[kk + 3][r] = v.w;
        }
        for (int t = tid; t < 4 * BN; t += 256) {
            int r = t >> 2, kk = (t & 3) << 2;
            float4 v = make_float4(0.f, 0.f, 0.f, 0.f);
            if (n0 + r < N)
                v = *(const float4*)(W + (size_t)(n0 + r) * K + (k0 + kk));
            Ws[kk + 0][r] = v.x; Ws[kk + 1][r] = v.y;
            Ws[kk + 2][r] = v.z; Ws[kk + 3][r] = v.w;
        }
        __syncthreads();
        #pragma unroll
        for (int kk = 0; kk < 16; ++kk) {
            float a[8], bb[TN];
            *(float4*)&a[0] = *(const float4*)&As[kk][ty * 8 + 0];
            *(float4*)&a[4] = *(const float4*)&As[kk][ty * 8 + 4];
            #pragma unroll
            for (int j = 0; j < TN; j += 4)
                *(float4*)&bb[j] = *(const float4*)&Ws[kk][tx * TN + j];
            #pragma unroll
            for (int i = 0; i < 8; ++i)
                #pragma unroll
                for (int j = 0; j < TN; ++j)
                    acc[i][j] += a[i] * bb[j];
        }
        __syncthreads();
    }

    #pragma unroll
    for (int i = 0; i < 8; ++i) {
        int m = m0 + ty * 8 + i;
        #pragma unroll
        for (int j = 0; j < TN; ++j) {
            int n = n0 + tx * TN + j;
            if (n < N) {
                float v = acc[i][j];
                if (bias) v += bias[n];
                if (act == 1) v = (v > 30.f) ? v : log1pf(expf(v));
                Cout[(size_t)m * N + n] = v;
            }
        }
    }
}

// ---------------------------------------------------------------------------
// Cross-attention core (per b, head, 8-query tile): softmax(QK^T/8) V
// Q,K,V,O in (B,L,C) layout, head h occupies columns h*64..h*64+63
// ---------------------------------------------------------------------------
__global__ __launch_bounds__(256)
void attn_kernel(const float* __restrict__ Q, const float* __restrict__ K,
                 const float* __restrict__ V, float* __restrict__ O)
{
    __shared__ __align__(16) float qs[8][68];
    __shared__ __align__(16) float sc[8][1025];
    int blk = blockIdx.x;           // 4096 = 8 * 4 * 128
    int qt = blk & 127;
    int h  = (blk >> 7) & 3;
    int b  = blk >> 9;
    int tid = threadIdx.x;
    int q0 = qt * 8;
    size_t rowbase = (size_t)b * 1024;

    for (int i = tid; i < 512; i += 256) {
        int r = i >> 6, d = i & 63;
        qs[r][d] = Q[(rowbase + q0 + r) * 256 + h * 64 + d];
    }
    __syncthreads();

    // scores
    for (int i = tid; i < 8192; i += 256) {
        int r = i & 7, kc = i >> 3;
        const float4* kp = (const float4*)(K + (rowbase + kc) * 256 + h * 64);
        const float4* qp = (const float4*)(&qs[r][0]);
        float s = 0.f;
        #pragma unroll
        for (int dd = 0; dd < 16; ++dd) {
            float4 kv = kp[dd];
            float4 qv = qp[dd];
            s += kv.x * qv.x + kv.y * qv.y + kv.z * qv.z + kv.w * qv.w;
        }
        sc[r][kc] = s * 0.125f;
    }
    __syncthreads();

    // softmax per row (32 lanes per row)
    {
        int r = tid >> 5, sub = tid & 31;
        float mx = -3.0e38f;
        for (int kc = sub; kc < 1024; kc += 32) mx = fmaxf(mx, sc[r][kc]);
        #pragma unroll
        for (int m = 16; m >= 1; m >>= 1) mx = fmaxf(mx, __shfl_xor(mx, m));
        float sum = 0.f;
        for (int kc = sub; kc < 1024; kc += 32) {
            float e = expf(sc[r][kc] - mx);
            sc[r][kc] = e;
            sum += e;
        }
        #pragma unroll
        for (int m = 16; m >= 1; m >>= 1) sum += __shfl_xor(sum, m);
        float inv = 1.f / sum;
        for (int kc = sub; kc < 1024; kc += 32) sc[r][kc] *= inv;
    }
    __syncthreads();

    // PV
    {
        int d = tid & 63, r0 = tid >> 6;  // rows r0 and r0+4
        const float* vp = V + rowbase * 256 + h * 64 + d;
        float a0 = 0.f, a1 = 0.f;
        for (int kc = 0; kc < 1024; ++kc) {
            float vv = vp[(size_t)kc * 256];
            a0 += sc[r0][kc] * vv;
            a1 += sc[r0 + 4][kc] * vv;
        }
        O[(rowbase + q0 + r0) * 256 + h * 64 + d] = a0;
        O[(rowbase + q0 + r0 + 4) * 256 + h * 64 + d] = a1;
    }
}

// ---------------------------------------------------------------------------
// Criss-cross attention, one block per (b, line, branch).
// ---------------------------------------------------------------------------
__global__ __launch_bounds__(256)
void cca_kernel(const float* __restrict__ QC, const float* __restrict__ KC,
                const float* __restrict__ VC,
                float* __restrict__ OH, float* __restrict__ OV)
{
    int rowid = blockIdx.x;       // 0..31
    int b     = blockIdx.y;
    int vert  = blockIdx.z;
    int base   = vert ? rowid : rowid * 32;
    int stride = vert ? 32 : 1;
    size_t pix0 = (size_t)b * 1024 + base;

    __shared__ float qs[32][65];
    __shared__ float ks[32][65];
    __shared__ float ps[32][33];

    int tid = threadIdx.x;
    for (int i = tid; i < 2048; i += 256) {
        int w = i >> 6, c = i & 63;
        size_t p = pix0 + (size_t)w * stride;
        qs[w][c] = QC[p * 64 + c];
        ks[w][c] = KC[p * 64 + c];
    }
    __syncthreads();

    {
        int wp = tid & 31, wr = tid >> 5;
        #pragma unroll
        for (int g = 0; g < 4; ++g) {
            int w = wr + g * 8;
            float s = 0.f;
            #pragma unroll
            for (int c = 0; c < 64; ++c) s += qs[w][c] * ks[wp][c];
            float mx = s;
            #pragma unroll
            for (int m = 16; m >= 1; m >>= 1) mx = fmaxf(mx, __shfl_xor(mx, m));
            float e = expf(s - mx);
            float sum = e;
            #pragma unroll
            for (int m = 16; m >= 1; m >>= 1) sum += __shfl_xor(sum, m);
            ps[w][wp] = e / sum;
        }
    }
    __syncthreads();

    {
        int c = tid;
        float acc[32];
        #pragma unroll
        for (int w = 0; w < 32; ++w) acc[w] = 0.f;
        for (int wp = 0; wp < 32; ++wp) {
            float vv = VC[(pix0 + (size_t)wp * stride) * 256 + c];
            #pragma unroll
            for (int w = 0; w < 32; ++w) acc[w] += ps[w][wp] * vv;
        }
        float* Oo = vert ? OV : OH;
        for (int w = 0; w < 32; ++w)
            Oo[(pix0 + (size_t)w * stride) * 256 + c] = acc[w];
    }
}

// Out = gamma*(OH+OV) + X
__global__ __launch_bounds__(256)
void combine_kernel(const float* __restrict__ OH, const float* __restrict__ OV,
                    const float* __restrict__ X, const float* __restrict__ gamma,
                    float* __restrict__ Out)
{
    int idx = blockIdx.x * 256 + threadIdx.x;
    float g = gamma[0];
    Out[idx] = g * (OH[idx] + OV[idx]) + X[idx];
}

// ---------------------------------------------------------------------------
// Causal depthwise conv(4) + bias + silu.  XZ: (B,L,1024), u = cols 0..511.
// ---------------------------------------------------------------------------
__global__ __launch_bounds__(256)
void conv_silu_kernel(const float* __restrict__ XZ, const float* __restrict__ cw,
                      const float* __restrict__ cb, float* __restrict__ U)
{
    int idx = blockIdx.x * 256 + threadIdx.x;   // B*L*512 = 4194304
    int d = idx & 511;
    int l = (idx >> 9) & 1023;
    int b = idx >> 19;
    float acc = cb[d];
    #pragma unroll
    for (int j = 0; j < 4; ++j) {
        int ls = l - 3 + j;
        if (ls >= 0)
            acc += XZ[((size_t)(b * 1024 + ls)) * 1024 + d] * cw[d * 4 + j];
    }
    U[idx] = acc / (1.f + expf(-acc));   // silu
}

// ---------------------------------------------------------------------------
// Chunked selective scan: h_t = a_t*h_{t-1} + b_t, linear in h.
// NC=32 chunks of TC=32. One thread per (b, chunk, d) holding all 16 states.
//
// Pass 1: per chunk compute P[n] = prod a_t, S[n] = response from h=0.
// Pass 2: serial stitch over chunks (tiny): Sbuf becomes per-chunk h_in.
// Pass 3: replay each chunk from h_in, emit y with fused epilogue
//         out = (y + u*Dp) * silu(z), written to XZ cols 0..511.
// ---------------------------------------------------------------------------
#define SCAN_NC 32
#define SCAN_TC 32

__global__ __launch_bounds__(256)
void scan_pass1(const float* __restrict__ DL, const float* __restrict__ U,
                const float* __restrict__ XD, const float* __restrict__ A_log,
                float* __restrict__ Pbuf, float* __restrict__ Sbuf)
{
    int idx = blockIdx.x * 256 + threadIdx.x;   // 8*32*512 = 131072
    int d = idx & 511;
    int c = (idx >> 9) & (SCAN_NC - 1);
    int b = idx >> 14;

    float A[16];
    #pragma unroll
    for (int g = 0; g < 4; ++g)
        *(float4*)&A[g * 4] = *(const float4*)(A_log + d * 16 + g * 4);
    #pragma unroll
    for (int n = 0; n < 16; ++n) A[n] = -expf(A[n]);

    float P[16], S[16];
    #pragma unroll
    for (int n = 0; n < 16; ++n) { P[n] = 1.f; S[n] = 0.f; }

    const float* dl = DL + ((size_t)b * 1024 + c * SCAN_TC) * 512 + d;
    const float* uu = U  + ((size_t)b * 1024 + c * SCAN_TC) * 512 + d;
    const float* xd = XD + (size_t)b * 1024 * 48 + (size_t)(c * SCAN_TC) * 48;

    for (int tt = 0; tt < SCAN_TC; ++tt) {
        float delta = dl[(size_t)tt * 512];
        float u     = uu[(size_t)tt * 512];
        float du = delta * u;
        float Bm[16];
        #pragma unroll
        for (int g = 0; g < 4; ++g)
            *(float4*)&Bm[g * 4] = *(const float4*)(xd + tt * 48 + 16 + g * 4);
        #pragma unroll
        for (int n = 0; n < 16; ++n) {
            float a = expf(delta * A[n]);
            S[n] = a * S[n] + du * Bm[n];
            P[n] *= a;
        }
    }

    size_t off = ((size_t)idx) * 16;
    #pragma unroll
    for (int g = 0; g < 4; ++g) {
        *(float4*)(Pbuf + off + g * 4) = *(const float4*)&P[g * 4];
        *(float4*)(Sbuf + off + g * 4) = *(const float4*)&S[g * 4];
    }
}

__global__ __launch_bounds__(256)
void scan_pass2(const float* __restrict__ Pbuf, float* __restrict__ Sbuf)
{
    int idx = blockIdx.x * 256 + threadIdx.x;   // 8*512*16 = 65536
    int dn = idx & 8191;
    int b  = idx >> 13;

    float h = 0.f;
    #pragma unroll 4
    for (int c = 0; c < SCAN_NC; ++c) {
        size_t off = (((size_t)b * SCAN_NC + c) * 512 * 16) + dn;
        float p = Pbuf[off];
        float s = Sbuf[off];
        Sbuf[off] = h;           // becomes h_in for chunk c
        h = p * h + s;
    }
}

__global__ __launch_bounds__(256)
void scan_pass3(const float* __restrict__ DL, const float* __restrict__ U,
                const float* __restrict__ XD, float* __restrict__ XZ,
                const float* __restrict__ A_log, const float* __restrict__ Dp,
                const float* __restrict__ Sbuf)
{
    int idx = blockIdx.x * 256 + threadIdx.x;   // 131072
    int d = idx & 511;
    int c = (idx >> 9) & (SCAN_NC - 1);
    int b = idx >> 14;

    float A[16], h[16];
    #pragma unroll
    for (int g = 0; g < 4; ++g)
        *(float4*)&A[g * 4] = *(const float4*)(A_log + d * 16 + g * 4);
    #pragma unroll
    for (int n = 0; n < 16; ++n) A[n] = -expf(A[n]);

    size_t soff = ((size_t)idx) * 16;
    #pragma unroll
    for (int g = 0; g < 4; ++g)
        *(float4*)&h[g * 4] = *(const float4*)(Sbuf + soff + g * 4);

    float Dval = Dp[d];

    const float* dl = DL + ((size_t)b * 1024 + c * SCAN_TC) * 512 + d;
    const float* uu = U  + ((size_t)b * 1024 + c * SCAN_TC) * 512 + d;
    const float* xd = XD + (size_t)b * 1024 * 48 + (size_t)(c * SCAN_TC) * 48;
    float* xz = XZ + ((size_t)b * 1024 + c * SCAN_TC) * 1024 + d;

    for (int tt = 0; tt < SCAN_TC; ++tt) {
        float delta = dl[(size_t)tt * 512];
        float u     = uu[(size_t)tt * 512];
        float du = delta * u;
        float Bm[16], Cm[16];
        #pragma unroll
        for (int g = 0; g < 4; ++g) {
            *(float4*)&Bm[g * 4] = *(const float4*)(xd + tt * 48 + 16 + g * 4);
            *(float4*)&Cm[g * 4] = *(const float4*)(xd + tt * 48 + 32 + g * 4);
        }
        float y = 0.f;
        #pragma unroll
        for (int n = 0; n < 16; ++n) {
            float a = expf(delta * A[n]);
            h[n] = a * h[n] + du * Bm[n];
            y += h[n] * Cm[n];
        }
        float z = xz[(size_t)tt * 1024 + 512];
        float out = (y + u * Dval) * (z / (1.f + expf(-z)));
        xz[(size_t)tt * 1024] = out;
    }
}

// ---------------------------------------------------------------------------
extern "C" void kernel_launch(void* const* d_in, const int* in_sizes, int n_in,
                              void* d_out, int out_size, void* d_ws, size_t ws_size,
                              hipStream_t stream)
{
    (void)in_sizes; (void)n_in; (void)out_size; (void)ws_size;
    const float* sam   = (const float*)d_in[0];
    const float* myn   = (const float*)d_in[1];
    const float* wq    = (const float*)d_in[2];
    const float* bq    = (const float*)d_in[3];
    const float* wk    = (const float*)d_in[4];
    const float* bk    = (const float*)d_in[5];
    const float* wv    = (const float*)d_in[6];
    const float* bv    = (const float*)d_in[7];
    const float* wo    = (const float*)d_in[8];
    const float* bo    = (const float*)d_in[9];
    const float* cqw   = (const float*)d_in[10];
    const float* cqb   = (const float*)d_in[11];
    const float* ckw   = (const float*)d_in[12];
    const float* ckb   = (const float*)d_in[13];
    const float* cvw   = (const float*)d_in[14];
    const float* cvb   = (const float*)d_in[15];
    const float* gamma = (const float*)d_in[16];
    const float* to_seq_w   = (const float*)d_in[17];
    const float* to_seq_b   = (const float*)d_in[18];
    const float* in_proj_w  = (const float*)d_in[19];
    const float* conv_w     = (const float*)d_in[20];
    const float* conv_b     = (const float*)d_in[21];
    const float* x_proj_w   = (const float*)d_in[22];
    const float* dt_w       = (const float*)d_in[23];
    const float* dt_b       = (const float*)d_in[24];
    const float* A_log      = (const float*)d_in[25];
    const float* Dp         = (const float*)d_in[26];
    const float* out_proj_w = (const float*)d_in[27];
    const float* from_seq_w = (const float*)d_in[28];
    const float* from_seq_b = (const float*)d_in[29];

    // workspace layout (floats); total 21,364,736 floats ~= 85.5 MB
    float* ws = (float*)d_ws;
    float* P0 = ws;                         // (B,L,C)  2097152
    float* P1 = ws + (size_t)2097152;       // (B,L,C)  2097152
    float* W0 = ws + (size_t)4194304;       // 8388608  (Q/K/V/O, then XZ)
    float* W1 = ws + (size_t)12582912;      // 4194304  (qc/kc/vc, then U)
    float* W2 = ws + (size_t)16777216;      // 4194304  (OH/OV, T, DL, MO)
    float* W4 = ws + (size_t)20971520;      // 393216   (XD)

    dim3 tb(32, 8, 1);
    transpose_kernel<<<dim3(32, 8, 8), tb, 0, stream>>>(sam, P0, 256, 1024);
    transpose_kernel<<<dim3(32, 8, 8), tb, 0, stream>>>(myn, P1, 256, 1024);

    auto lin128 = [&](const float* A, int lda, const float* Wp, const float* bias,
                      float* Cout, int N, int K, int act) {
        linear_kernel<128, 8><<<dim3((N + 127) / 128, 64), 256, 0, stream>>>(
            A, lda, Wp, bias, Cout, 8192, N, K, act);
    };
    auto lin64 = [&](const float* A, int lda, const float* Wp, const float* bias,
                     float* Cout, int N, int K, int act) {
        linear_kernel<64, 4><<<dim3((N + 63) / 64, 64), 256, 0, stream>>>(
            A, lda, Wp, bias, Cout, 8192, N, K, act);
    };

    // ---- cross attention ----
    float* Qb = W0;
    float* Kb = W0 + 2097152;
    float* Vb = W0 + 4194304;
    float* Ob = W0 + 6291456;
    lin128(P0, 256, wq, bq, Qb, 256, 256, 0);
    lin128(P1, 256, wk, bk, Kb, 256, 256, 0);
    lin128(P1, 256, wv, bv, Vb, 256, 256, 0);
    attn_kernel<<<4096, 256, 0, stream>>>(Qb, Kb, Vb, Ob);
    lin128(Ob, 256, wo, bo, P0, 256, 256, 0);      // fusion -> P0

    // ---- criss-cross attention ----
    float* QC = W1;
    float* KC = W1 + 524288;
    float* VC = W1 + 1048576;
    lin64 (P0, 256, cqw, cqb, QC, 64, 256, 0);
    lin64 (P0, 256, ckw, ckb, KC, 64, 256, 0);
    lin128(P0, 256, cvw, cvb, VC, 256, 256, 0);
    float* OH = W2;
    float* OV = W2 + 2097152;
    cca_kernel<<<dim3(32, 8, 2), 256, 0, stream>>>(QC, KC, VC, OH, OV);
    combine_kernel<<<8192, 256, 0, stream>>>(OH, OV, P0, gamma, P1); // spatial -> P1

    // ---- 2x mamba blocks ----
    for (int i = 0; i < 2; ++i) {
        const float* Sin = (i == 0) ? P1 : P0;
        float* Sout      = (i == 0) ? P0 : P1;
        float* T = W2;
        lin128(Sin, 256, to_seq_w + (size_t)i * 65536, to_seq_b + i * 256, T, 256, 256, 0);
        lin128(T, 256, in_proj_w + (size_t)i * 262144, nullptr, W0, 1024, 256, 0); // XZ
        conv_silu_kernel<<<16384, 256, 0, stream>>>(W0, conv_w + (size_t)i * 2048,
                                                    conv_b + i * 512, W1);         // U
        lin64 (W1, 512, x_proj_w + (size_t)i * 24576, nullptr, W4, 48, 512, 0);    // XD
        lin128(W4, 48, dt_w + (size_t)i * 8192, dt_b + i * 512, W2, 512, 16, 1);   // DL (softplus)

        // chunked scan: Pbuf = Sout region (free until from_seq), Sbuf = d_out
        float* Pbuf = Sout;
        float* Sbuf = (float*)d_out;
        scan_pass1<<<512, 256, 0, stream>>>(W2, W1, W4,
                                            A_log + (size_t)i * 8192, Pbuf, Sbuf);
        scan_pass2<<<256, 256, 0, stream>>>(Pbuf, Sbuf);
        scan_pass3<<<512, 256, 0, stream>>>(W2, W1, W4, W0,
                                            A_log + (size_t)i * 8192, Dp + i * 512,
                                            Sbuf);

        lin128(W0, 1024, out_proj_w + (size_t)i * 131072, nullptr, W2, 256, 512, 0); // MO
        lin128(W2, 256, from_seq_w + (size_t)i * 65536, from_seq_b + i * 256, Sout, 256, 256, 0);
    }

    // final (B,L,C) -> (B,C,L)
    transpose_kernel<<<dim3(8, 32, 8), tb, 0, stream>>>(P1, (float*)d_out, 1024, 256);
}

// Round 3
// 1319.457 us; speedup vs baseline: 2.6016x; 1.5719x over previous
//
#include <hip/hip_runtime.h>
#include <math.h>

// Problem constants
// B=8, C=256, H=32, W=32, L=1024, HEADS=4 (dh=64), IC=64,
// D_INNER=512, DT_RANK=16, D_STATE=16, D_CONV=4, DEPTH=2, M=B*L=8192

typedef short short8 __attribute__((ext_vector_type(8)));
typedef float f32x4  __attribute__((ext_vector_type(4)));

// f32 -> bf16 bits, round-to-nearest-even
__device__ __forceinline__ unsigned short f2bfu(float x)
{
    union { float f; unsigned int u; } c; c.f = x;
    unsigned int u = c.u + 0x7FFFu + ((c.u >> 16) & 1u);
    return (unsigned short)(u >> 16);
}

// ---------------------------------------------------------------------------
// Batched transpose: in (Bn, R, S) -> out (Bn, S, R)
// ---------------------------------------------------------------------------
__global__ __launch_bounds__(256)
void transpose_kernel(const float* __restrict__ in, float* __restrict__ out,
                      int R, int S)
{
    __shared__ float tile[32][33];
    int b  = blockIdx.z;
    int s0 = blockIdx.x * 32, r0 = blockIdx.y * 32;
    const float* inb = in + (size_t)b * R * S;
    float* outb = out + (size_t)b * R * S;
    int tx = threadIdx.x, ty = threadIdx.y;  // 32 x 8
    #pragma unroll
    for (int j = 0; j < 32; j += 8)
        tile[ty + j][tx] = inb[(size_t)(r0 + ty + j) * S + (s0 + tx)];
    __syncthreads();
    #pragma unroll
    for (int j = 0; j < 32; j += 8)
        outb[(size_t)(s0 + ty + j) * R + (r0 + tx)] = tile[tx][ty + j];
}

// ---------------------------------------------------------------------------
// Generic linear: Cout[M,N] = act(A[M,K](lda) @ W[N,K]^T + bias)
// act: 0 = none, 1 = softplus.  16x16 threads, micro-tile TM x TN.
// BM = 16*TM, BN = 16*TN. Requires M % BM == 0, K % 16 == 0, lda % 4 == 0.
// ---------------------------------------------------------------------------
template <int BM, int BN, int TM, int TN>
__global__ __launch_bounds__(256)
void linear_kernel(const float* __restrict__ A, int lda,
                   const float* __restrict__ W, const float* __restrict__ bias,
                   float* __restrict__ Cout,
                   int M, int N, int K, int act)
{
    __shared__ __align__(16) float As[16][BM + 4];
    __shared__ __align__(16) float Ws[16][BN + 4];
    int tid = threadIdx.x;
    int tx = tid & 15, ty = tid >> 4;
    int m0 = blockIdx.y * BM, n0 = blockIdx.x * BN;

    float acc[TM][TN];
    #pragma unroll
    for (int i = 0; i < TM; ++i)
        #pragma unroll
        for (int j = 0; j < TN; ++j) acc[i][j] = 0.f;

    for (int k0 = 0; k0 < K; k0 += 16) {
        for (int t = tid; t < 4 * BM; t += 256) {
            int r = t >> 2, kk = (t & 3) << 2;
            float4 v = *(const float4*)(A + (size_t)(m0 + r) * lda + (k0 + kk));
            As[kk + 0][r] = v.x; As[kk + 1][r] = v.y;
            As[kk + 2][r] = v.z; As[kk + 3][r] = v.w;
        }
        for (int t = tid; t < 4 * BN; t += 256) {
            int r = t >> 2, kk = (t & 3) << 2;
            float4 v = make_float4(0.f, 0.f, 0.f, 0.f);
            if (n0 + r < N)
                v = *(const float4*)(W + (size_t)(n0 + r) * K + (k0 + kk));
            Ws[kk + 0][r] = v.x; Ws[kk + 1][r] = v.y;
            Ws[kk + 2][r] = v.z; Ws[kk + 3][r] = v.w;
        }
        __syncthreads();
        #pragma unroll
        for (int kk = 0; kk < 16; ++kk) {
            float a[TM], bb[TN];
            #pragma unroll
            for (int i = 0; i < TM; i += 4)
                *(float4*)&a[i] = *(const float4*)&As[kk][ty * TM + i];
            #pragma unroll
            for (int j = 0; j < TN; j += 4)
                *(float4*)&bb[j] = *(const float4*)&Ws[kk][tx * TN + j];
            #pragma unroll
            for (int i = 0; i < TM; ++i)
                #pragma unroll
                for (int j = 0; j < TN; ++j)
                    acc[i][j] += a[i] * bb[j];
        }
        __syncthreads();
    }

    #pragma unroll
    for (int i = 0; i < TM; ++i) {
        int m = m0 + ty * TM + i;
        #pragma unroll
        for (int j = 0; j < TN; ++j) {
            int n = n0 + tx * TN + j;
            if (n < N) {
                float v = acc[i][j];
                if (bias) v += bias[n];
                if (act == 1) v = (v > 30.f) ? v : log1pf(expf(v));
                Cout[(size_t)m * N + n] = v;
            }
        }
    }
}

// ---------------------------------------------------------------------------
// MFMA flash cross-attention: one block per (b, h, 16-q-row tile).
// S = (Q*0.125) @ K^T via mfma_f32_16x16x32_bf16, online softmax over 16
// chunks of 64 kc, PV via MFMA with V chunk transposed into LDS (bf16).
// Layouts (verified, guide §3): A[m=lane&15][k=quad*8+j],
// B[n=lane&15][k=quad*8+j], D: col=lane&15, row=quad*4+reg.
// ---------------------------------------------------------------------------
__global__ __launch_bounds__(256)
void attn_mfma_kernel(const float* __restrict__ Q, const float* __restrict__ K,
                      const float* __restrict__ V, float* __restrict__ O)
{
    __shared__ unsigned short qs[16][72];   // Q tile, bf16, padded
    __shared__ unsigned short pb[16][72];   // P chunk, bf16
    __shared__ unsigned short vt[64][72];   // V^T chunk, bf16
    __shared__ float wred[4][16];
    __shared__ float wsum[4][16];
    __shared__ float mrun[16];
    __shared__ float lrun[16];

    int qt = blockIdx.x, h = blockIdx.y, b = blockIdx.z;
    int tid  = threadIdx.x;
    int wave = tid >> 6, lane = tid & 63;
    int quad = lane >> 4, l15 = lane & 15;
    size_t rowbase = (size_t)b * 1024;
    int q0 = qt * 16;
    const float* Qb = Q + (rowbase + q0) * 256 + h * 64;
    const float* Kb = K + rowbase * 256 + h * 64;
    const float* Vb = V + rowbase * 256 + h * 64;

    // stage Q (scaled by dh^-0.5 = 0.125) as bf16
    {
        int r = tid >> 4, c4 = (tid & 15) * 4;
        float4 v = *(const float4*)(Qb + (size_t)r * 256 + c4);
        qs[r][c4 + 0] = f2bfu(v.x * 0.125f);
        qs[r][c4 + 1] = f2bfu(v.y * 0.125f);
        qs[r][c4 + 2] = f2bfu(v.z * 0.125f);
        qs[r][c4 + 3] = f2bfu(v.w * 0.125f);
    }
    if (tid < 16) { mrun[tid] = -1e30f; lrun[tid] = 0.f; }
    __syncthreads();

    short8 qfrag0 = *(const short8*)&qs[l15][quad * 8];
    short8 qfrag1 = *(const short8*)&qs[l15][quad * 8 + 32];

    f32x4 accO = {0.f, 0.f, 0.f, 0.f};
    float mnew4[4], alpha4[4], psum4[4];

    for (int ch = 0; ch < 16; ++ch) {
        int kc0 = ch * 64;
        // ---- A: stage V^T chunk; compute S tile ----
        {
            int f = tid;
            #pragma unroll
            for (int p = 0; p < 4; ++p, f += 256) {
                int kc = f >> 4, c4 = (f & 15) * 4;
                float4 v = *(const float4*)(Vb + (size_t)(kc0 + kc) * 256 + c4);
                vt[c4 + 0][kc] = f2bfu(v.x);
                vt[c4 + 1][kc] = f2bfu(v.y);
                vt[c4 + 2][kc] = f2bfu(v.z);
                vt[c4 + 3][kc] = f2bfu(v.w);
            }
        }
        f32x4 accS = {0.f, 0.f, 0.f, 0.f};
        {
            int kc = kc0 + wave * 16 + l15;
            const float* kp = Kb + (size_t)kc * 256 + quad * 8;
            #pragma unroll
            for (int ks = 0; ks < 2; ++ks) {
                float4 k0v = *(const float4*)(kp + ks * 32);
                float4 k1v = *(const float4*)(kp + ks * 32 + 4);
                short8 bf;
                bf[0] = (short)f2bfu(k0v.x); bf[1] = (short)f2bfu(k0v.y);
                bf[2] = (short)f2bfu(k0v.z); bf[3] = (short)f2bfu(k0v.w);
                bf[4] = (short)f2bfu(k1v.x); bf[5] = (short)f2bfu(k1v.y);
                bf[6] = (short)f2bfu(k1v.z); bf[7] = (short)f2bfu(k1v.w);
                accS = __builtin_amdgcn_mfma_f32_16x16x32_bf16(
                    ks == 0 ? qfrag0 : qfrag1, bf, accS, 0, 0, 0);
            }
        }
        // per-reg (= per-row) max across the 16 lanes of the quad
        {
            float m4[4];
            #pragma unroll
            for (int r = 0; r < 4; ++r) {
                float m = accS[r];
                m = fmaxf(m, __shfl_xor(m, 1));
                m = fmaxf(m, __shfl_xor(m, 2));
                m = fmaxf(m, __shfl_xor(m, 4));
                m = fmaxf(m, __shfl_xor(m, 8));
                m4[r] = m;
            }
            if (l15 == 0)
                #pragma unroll
                for (int r = 0; r < 4; ++r) wred[wave][quad * 4 + r] = m4[r];
        }
        __syncthreads();   // (1) publish wred; vt now visible too

        // ---- B: online softmax update, write P chunk (bf16) ----
        #pragma unroll
        for (int r = 0; r < 4; ++r) {
            int row = quad * 4 + r;
            float mrow = fmaxf(fmaxf(wred[0][row], wred[1][row]),
                               fmaxf(wred[2][row], wred[3][row]));
            float mold = mrun[row];
            float mnew = fmaxf(mold, mrow);
            float alpha = expf(mold - mnew);
            float p = expf(accS[r] - mnew);
            pb[row][wave * 16 + l15] = f2bfu(p);
            float ps = p;
            ps += __shfl_xor(ps, 1);
            ps += __shfl_xor(ps, 2);
            ps += __shfl_xor(ps, 4);
            ps += __shfl_xor(ps, 8);
            accO[r] *= alpha;
            mnew4[r] = mnew; alpha4[r] = alpha; psum4[r] = ps;
        }
        if (l15 == 0)
            #pragma unroll
            for (int r = 0; r < 4; ++r) wsum[wave][quad * 4 + r] = psum4[r];
        __syncthreads();   // (2) publish pb + wsum

        // ---- C: stats update (wave 0) + PV MFMAs ----
        if (wave == 0 && l15 == 0) {
            #pragma unroll
            for (int r = 0; r < 4; ++r) {
                int row = quad * 4 + r;
                mrun[row] = mnew4[r];
                lrun[row] = lrun[row] * alpha4[r] +
                            wsum[0][row] + wsum[1][row] + wsum[2][row] + wsum[3][row];
            }
        }
        #pragma unroll
        for (int ks = 0; ks < 2; ++ks) {
            short8 a  = *(const short8*)&pb[l15][quad * 8 + ks * 32];
            short8 bv = *(const short8*)&vt[wave * 16 + l15][quad * 8 + ks * 32];
            accO = __builtin_amdgcn_mfma_f32_16x16x32_bf16(a, bv, accO, 0, 0, 0);
        }
        __syncthreads();   // (3) protect vt/pb for next chunk
    }

    // epilogue: O[row][d] = accO / l
    #pragma unroll
    for (int r = 0; r < 4; ++r) {
        int row = quad * 4 + r;
        float o = accO[r] / lrun[row];
        O[(rowbase + q0 + row) * 256 + h * 64 + wave * 16 + l15] = o;
    }
}

// ---------------------------------------------------------------------------
// Criss-cross attention, one block per (b, line, branch).
// ---------------------------------------------------------------------------
__global__ __launch_bounds__(256)
void cca_kernel(const float* __restrict__ QC, const float* __restrict__ KC,
                const float* __restrict__ VC,
                float* __restrict__ OH, float* __restrict__ OV)
{
    int rowid = blockIdx.x;       // 0..31
    int b     = blockIdx.y;
    int vert  = blockIdx.z;
    int base   = vert ? rowid : rowid * 32;
    int stride = vert ? 32 : 1;
    size_t pix0 = (size_t)b * 1024 + base;

    __shared__ float qs[32][65];
    __shared__ float ks[32][65];
    __shared__ float ps[32][33];

    int tid = threadIdx.x;
    for (int i = tid; i < 2048; i += 256) {
        int w = i >> 6, c = i & 63;
        size_t p = pix0 + (size_t)w * stride;
        qs[w][c] = QC[p * 64 + c];
        ks[w][c] = KC[p * 64 + c];
    }
    __syncthreads();

    {
        int wp = tid & 31, wr = tid >> 5;
        #pragma unroll
        for (int g = 0; g < 4; ++g) {
            int w = wr + g * 8;
            float s = 0.f;
            #pragma unroll
            for (int c = 0; c < 64; ++c) s += qs[w][c] * ks[wp][c];
            float mx = s;
            #pragma unroll
            for (int m = 16; m >= 1; m >>= 1) mx = fmaxf(mx, __shfl_xor(mx, m));
            float e = expf(s - mx);
            float sum = e;
            #pragma unroll
            for (int m = 16; m >= 1; m >>= 1) sum += __shfl_xor(sum, m);
            ps[w][wp] = e / sum;
        }
    }
    __syncthreads();

    {
        int c = tid;
        float acc[32];
        #pragma unroll
        for (int w = 0; w < 32; ++w) acc[w] = 0.f;
        for (int wp = 0; wp < 32; ++wp) {
            float vv = VC[(pix0 + (size_t)wp * stride) * 256 + c];
            #pragma unroll
            for (int w = 0; w < 32; ++w) acc[w] += ps[w][wp] * vv;
        }
        float* Oo = vert ? OV : OH;
        for (int w = 0; w < 32; ++w)
            Oo[(pix0 + (size_t)w * stride) * 256 + c] = acc[w];
    }
}

// Out = gamma*(OH+OV) + X
__global__ __launch_bounds__(256)
void combine_kernel(const float* __restrict__ OH, const float* __restrict__ OV,
                    const float* __restrict__ X, const float* __restrict__ gamma,
                    float* __restrict__ Out)
{
    int idx = blockIdx.x * 256 + threadIdx.x;
    float g = gamma[0];
    Out[idx] = g * (OH[idx] + OV[idx]) + X[idx];
}

// ---------------------------------------------------------------------------
// Causal depthwise conv(4) + bias + silu.  XZ: (B,L,1024), u = cols 0..511.
// ---------------------------------------------------------------------------
__global__ __launch_bounds__(256)
void conv_silu_kernel(const float* __restrict__ XZ, const float* __restrict__ cw,
                      const float* __restrict__ cb, float* __restrict__ U)
{
    int idx = blockIdx.x * 256 + threadIdx.x;   // B*L*512 = 4194304
    int d = idx & 511;
    int l = (idx >> 9) & 1023;
    int b = idx >> 19;
    float acc = cb[d];
    #pragma unroll
    for (int j = 0; j < 4; ++j) {
        int ls = l - 3 + j;
        if (ls >= 0)
            acc += XZ[((size_t)(b * 1024 + ls)) * 1024 + d] * cw[d * 4 + j];
    }
    U[idx] = acc / (1.f + expf(-acc));   // silu
}

// ---------------------------------------------------------------------------
// Chunked selective scan (3 passes), see R2.
// ---------------------------------------------------------------------------
#define SCAN_NC 32
#define SCAN_TC 32

__global__ __launch_bounds__(256)
void scan_pass1(const float* __restrict__ DL, const float* __restrict__ U,
                const float* __restrict__ XD, const float* __restrict__ A_log,
                float* __restrict__ Pbuf, float* __restrict__ Sbuf)
{
    int idx = blockIdx.x * 256 + threadIdx.x;   // 8*32*512 = 131072
    int d = idx & 511;
    int c = (idx >> 9) & (SCAN_NC - 1);
    int b = idx >> 14;

    float A[16];
    #pragma unroll
    for (int g = 0; g < 4; ++g)
        *(float4*)&A[g * 4] = *(const float4*)(A_log + d * 16 + g * 4);
    #pragma unroll
    for (int n = 0; n < 16; ++n) A[n] = -expf(A[n]);

    float P[16], S[16];
    #pragma unroll
    for (int n = 0; n < 16; ++n) { P[n] = 1.f; S[n] = 0.f; }

    const float* dl = DL + ((size_t)b * 1024 + c * SCAN_TC) * 512 + d;
    const float* uu = U  + ((size_t)b * 1024 + c * SCAN_TC) * 512 + d;
    const float* xd = XD + (size_t)b * 1024 * 48 + (size_t)(c * SCAN_TC) * 48;

    for (int tt = 0; tt < SCAN_TC; ++tt) {
        float delta = dl[(size_t)tt * 512];
        float u     = uu[(size_t)tt * 512];
        float du = delta * u;
        float Bm[16];
        #pragma unroll
        for (int g = 0; g < 4; ++g)
            *(float4*)&Bm[g * 4] = *(const float4*)(xd + tt * 48 + 16 + g * 4);
        #pragma unroll
        for (int n = 0; n < 16; ++n) {
            float a = expf(delta * A[n]);
            S[n] = a * S[n] + du * Bm[n];
            P[n] *= a;
        }
    }

    size_t off = ((size_t)idx) * 16;
    #pragma unroll
    for (int g = 0; g < 4; ++g) {
        *(float4*)(Pbuf + off + g * 4) = *(const float4*)&P[g * 4];
        *(float4*)(Sbuf + off + g * 4) = *(const float4*)&S[g * 4];
    }
}

__global__ __launch_bounds__(256)
void scan_pass2(const float* __restrict__ Pbuf, float* __restrict__ Sbuf)
{
    int idx = blockIdx.x * 256 + threadIdx.x;   // 8*512*16 = 65536
    int dn = idx & 8191;
    int b  = idx >> 13;

    float h = 0.f;
    #pragma unroll 4
    for (int c = 0; c < SCAN_NC; ++c) {
        size_t off = (((size_t)b * SCAN_NC + c) * 512 * 16) + dn;
        float p = Pbuf[off];
        float s = Sbuf[off];
        Sbuf[off] = h;           // becomes h_in for chunk c
        h = p * h + s;
    }
}

__global__ __launch_bounds__(256)
void scan_pass3(const float* __restrict__ DL, const float* __restrict__ U,
                const float* __restrict__ XD, float* __restrict__ XZ,
                const float* __restrict__ A_log, const float* __restrict__ Dp,
                const float* __restrict__ Sbuf)
{
    int idx = blockIdx.x * 256 + threadIdx.x;   // 131072
    int d = idx & 511;
    int c = (idx >> 9) & (SCAN_NC - 1);
    int b = idx >> 14;

    float A[16], h[16];
    #pragma unroll
    for (int g = 0; g < 4; ++g)
        *(float4*)&A[g * 4] = *(const float4*)(A_log + d * 16 + g * 4);
    #pragma unroll
    for (int n = 0; n < 16; ++n) A[n] = -expf(A[n]);

    size_t soff = ((size_t)idx) * 16;
    #pragma unroll
    for (int g = 0; g < 4; ++g)
        *(float4*)&h[g * 4] = *(const float4*)(Sbuf + soff + g * 4);

    float Dval = Dp[d];

    const float* dl = DL + ((size_t)b * 1024 + c * SCAN_TC) * 512 + d;
    const float* uu = U  + ((size_t)b * 1024 + c * SCAN_TC) * 512 + d;
    const float* xd = XD + (size_t)b * 1024 * 48 + (size_t)(c * SCAN_TC) * 48;
    float* xz = XZ + ((size_t)b * 1024 + c * SCAN_TC) * 1024 + d;

    for (int tt = 0; tt < SCAN_TC; ++tt) {
        float delta = dl[(size_t)tt * 512];
        float u     = uu[(size_t)tt * 512];
        float du = delta * u;
        float Bm[16], Cm[16];
        #pragma unroll
        for (int g = 0; g < 4; ++g) {
            *(float4*)&Bm[g * 4] = *(const float4*)(xd + tt * 48 + 16 + g * 4);
            *(float4*)&Cm[g * 4] = *(const float4*)(xd + tt * 48 + 32 + g * 4);
        }
        float y = 0.f;
        #pragma unroll
        for (int n = 0; n < 16; ++n) {
            float a = expf(delta * A[n]);
            h[n] = a * h[n] + du * Bm[n];
            y += h[n] * Cm[n];
        }
        float z = xz[(size_t)tt * 1024 + 512];
        float out = (y + u * Dval) * (z / (1.f + expf(-z)));
        xz[(size_t)tt * 1024] = out;
    }
}

// ---------------------------------------------------------------------------
extern "C" void kernel_launch(void* const* d_in, const int* in_sizes, int n_in,
                              void* d_out, int out_size, void* d_ws, size_t ws_size,
                              hipStream_t stream)
{
    (void)in_sizes; (void)n_in; (void)out_size; (void)ws_size;
    const float* sam   = (const float*)d_in[0];
    const float* myn   = (const float*)d_in[1];
    const float* wq    = (const float*)d_in[2];
    const float* bq    = (const float*)d_in[3];
    const float* wk    = (const float*)d_in[4];
    const float* bk    = (const float*)d_in[5];
    const float* wv    = (const float*)d_in[6];
    const float* bv    = (const float*)d_in[7];
    const float* wo    = (const float*)d_in[8];
    const float* bo    = (const float*)d_in[9];
    const float* cqw   = (const float*)d_in[10];
    const float* cqb   = (const float*)d_in[11];
    const float* ckw   = (const float*)d_in[12];
    const float* ckb   = (const float*)d_in[13];
    const float* cvw   = (const float*)d_in[14];
    const float* cvb   = (const float*)d_in[15];
    const float* gamma = (const float*)d_in[16];
    const float* to_seq_w   = (const float*)d_in[17];
    const float* to_seq_b   = (const float*)d_in[18];
    const float* in_proj_w  = (const float*)d_in[19];
    const float* conv_w     = (const float*)d_in[20];
    const float* conv_b     = (const float*)d_in[21];
    const float* x_proj_w   = (const float*)d_in[22];
    const float* dt_w       = (const float*)d_in[23];
    const float* dt_b       = (const float*)d_in[24];
    const float* A_log      = (const float*)d_in[25];
    const float* Dp         = (const float*)d_in[26];
    const float* out_proj_w = (const float*)d_in[27];
    const float* from_seq_w = (const float*)d_in[28];
    const float* from_seq_b = (const float*)d_in[29];

    // workspace layout (floats); total ~85.5 MB
    float* ws = (float*)d_ws;
    float* P0 = ws;                         // (B,L,C)  2097152
    float* P1 = ws + (size_t)2097152;       // (B,L,C)  2097152
    float* W0 = ws + (size_t)4194304;       // 8388608  (Q/K/V/O, then XZ)
    float* W1 = ws + (size_t)12582912;      // 4194304  (qc/kc/vc, then U)
    float* W2 = ws + (size_t)16777216;      // 4194304  (OH/OV, T, DL, MO)
    float* W4 = ws + (size_t)20971520;      // 393216   (XD)

    dim3 tb(32, 8, 1);
    transpose_kernel<<<dim3(32, 8, 8), tb, 0, stream>>>(sam, P0, 256, 1024);
    transpose_kernel<<<dim3(32, 8, 8), tb, 0, stream>>>(myn, P1, 256, 1024);

    // N=1024 GEMM: 128x128 tiles -> 512 blocks
    auto linWide = [&](const float* A, int lda, const float* Wp, const float* bias,
                       float* Cout, int N, int K, int act) {
        linear_kernel<128, 128, 8, 8><<<dim3(N / 128, 64), 256, 0, stream>>>(
            A, lda, Wp, bias, Cout, 8192, N, K, act);
    };
    // N in {256,512} GEMM: 128x64 tiles -> 256/512 blocks (full GPU)
    auto linMid = [&](const float* A, int lda, const float* Wp, const float* bias,
                      float* Cout, int N, int K, int act) {
        linear_kernel<128, 64, 8, 4><<<dim3((N + 63) / 64, 64), 256, 0, stream>>>(
            A, lda, Wp, bias, Cout, 8192, N, K, act);
    };
    // N <= 64 GEMM: 64x64 tiles -> 128 blocks
    auto linSmall = [&](const float* A, int lda, const float* Wp, const float* bias,
                        float* Cout, int N, int K, int act) {
        linear_kernel<64, 64, 4, 4><<<dim3(1, 128), 256, 0, stream>>>(
            A, lda, Wp, bias, Cout, 8192, N, K, act);
    };

    // ---- cross attention ----
    float* Qb = W0;
    float* Kb = W0 + 2097152;
    float* Vb = W0 + 4194304;
    float* Ob = W0 + 6291456;
    linMid(P0, 256, wq, bq, Qb, 256, 256, 0);
    linMid(P1, 256, wk, bk, Kb, 256, 256, 0);
    linMid(P1, 256, wv, bv, Vb, 256, 256, 0);
    attn_mfma_kernel<<<dim3(64, 4, 8), 256, 0, stream>>>(Qb, Kb, Vb, Ob);
    linMid(Ob, 256, wo, bo, P0, 256, 256, 0);      // fusion -> P0

    // ---- criss-cross attention ----
    float* QC = W1;
    float* KC = W1 + 524288;
    float* VC = W1 + 1048576;
    linSmall(P0, 256, cqw, cqb, QC, 64, 256, 0);
    linSmall(P0, 256, ckw, ckb, KC, 64, 256, 0);
    linMid (P0, 256, cvw, cvb, VC, 256, 256, 0);
    float* OH = W2;
    float* OV = W2 + 2097152;
    cca_kernel<<<dim3(32, 8, 2), 256, 0, stream>>>(QC, KC, VC, OH, OV);
    combine_kernel<<<8192, 256, 0, stream>>>(OH, OV, P0, gamma, P1); // spatial -> P1

    // ---- 2x mamba blocks ----
    for (int i = 0; i < 2; ++i) {
        const float* Sin = (i == 0) ? P1 : P0;
        float* Sout      = (i == 0) ? P0 : P1;
        float* T = W2;
        linMid(Sin, 256, to_seq_w + (size_t)i * 65536, to_seq_b + i * 256, T, 256, 256, 0);
        linWide(T, 256, in_proj_w + (size_t)i * 262144, nullptr, W0, 1024, 256, 0); // XZ
        conv_silu_kernel<<<16384, 256, 0, stream>>>(W0, conv_w + (size_t)i * 2048,
                                                    conv_b + i * 512, W1);          // U
        linSmall(W1, 512, x_proj_w + (size_t)i * 24576, nullptr, W4, 48, 512, 0);   // XD
        linMid(W4, 48, dt_w + (size_t)i * 8192, dt_b + i * 512, W2, 512, 16, 1);    // DL (softplus)

        // chunked scan: Pbuf = Sout region (free until from_seq), Sbuf = d_out
        float* Pbuf = Sout;
        float* Sbuf = (float*)d_out;
        scan_pass1<<<512, 256, 0, stream>>>(W2, W1, W4,
                                            A_log + (size_t)i * 8192, Pbuf, Sbuf);
        scan_pass2<<<256, 256, 0, stream>>>(Pbuf, Sbuf);
        scan_pass3<<<512, 256, 0, stream>>>(W2, W1, W4, W0,
                                            A_log + (size_t)i * 8192, Dp + i * 512,
                                            Sbuf);

        linMid(W0, 1024, out_proj_w + (size_t)i * 131072, nullptr, W2, 256, 512, 0); // MO
        linMid(W2, 256, from_seq_w + (size_t)i * 65536, from_seq_b + i * 256, Sout, 256, 256, 0);
    }

    // final (B,L,C) -> (B,C,L)
    transpose_kernel<<<dim3(8, 32, 8), tb, 0, stream>>>(P1, (float*)d_out, 1024, 256);
}

// Round 4
// 937.333 us; speedup vs baseline: 3.6622x; 1.4077x over previous
//
#include <hip/hip_runtime.h>
#include <math.h>

// Problem constants
// B=8, C=256, H=32, W=32, L=1024, HEADS=4 (dh=64), IC=64,
// D_INNER=512, DT_RANK=16, D_STATE=16, D_CONV=4, DEPTH=2, M=B*L=8192

typedef short short8 __attribute__((ext_vector_type(8)));
typedef float f32x4  __attribute__((ext_vector_type(4)));

// f32 -> bf16 bits, round-to-nearest-even
__device__ __forceinline__ unsigned short f2bfu(float x)
{
    union { float f; unsigned int u; } c; c.f = x;
    unsigned int u = c.u + 0x7FFFu + ((c.u >> 16) & 1u);
    return (unsigned short)(u >> 16);
}

// ---------------------------------------------------------------------------
// Batched transpose: in (Bn, R, S) -> out (Bn, S, R)
// ---------------------------------------------------------------------------
__global__ __launch_bounds__(256)
void transpose_kernel(const float* __restrict__ in, float* __restrict__ out,
                      int R, int S)
{
    __shared__ float tile[32][33];
    int b  = blockIdx.z;
    int s0 = blockIdx.x * 32, r0 = blockIdx.y * 32;
    const float* inb = in + (size_t)b * R * S;
    float* outb = out + (size_t)b * R * S;
    int tx = threadIdx.x, ty = threadIdx.y;  // 32 x 8
    #pragma unroll
    for (int j = 0; j < 32; j += 8)
        tile[ty + j][tx] = inb[(size_t)(r0 + ty + j) * S + (s0 + tx)];
    __syncthreads();
    #pragma unroll
    for (int j = 0; j < 32; j += 8)
        outb[(size_t)(s0 + ty + j) * R + (r0 + tx)] = tile[tx][ty + j];
}

// ---------------------------------------------------------------------------
// MFMA bf16 GEMM: C[M,N] = A[M,K](lda, fp32->bf16 staged) @ W[N,K]^T + bias
// BM = 32*MF (MF=2 -> 64, MF=4 -> 128), BN = 64, K chunk = 64.
// Requires: K % 64 == 0, N % 64 == 0, M % BM == 0, lda % 4 == 0.
// 4 waves: 2x2 wave grid; wave computes (16*MF) x 32 via 16x16x32 MFMAs.
// Fragment layouts per guide §3 (verified): A[m=lane&15][k=quad*8+j],
// B[n=lane&15][k=quad*8+j], D col=lane&15, row=quad*4+reg.
// ---------------------------------------------------------------------------
template <int MF>
__global__ __launch_bounds__(256)
void gemm_mfma_kernel(const float* __restrict__ A, int lda,
                      const float* __restrict__ W, const float* __restrict__ bias,
                      float* __restrict__ C, int N, int K)
{
    constexpr int BM = 32 * MF;
    __shared__ unsigned short As[BM][72];   // +8 pad: 2-way bank alias (free)
    __shared__ unsigned short Ws[64][72];
    int tid = threadIdx.x;
    int wave = tid >> 6, lane = tid & 63;
    int quad = lane >> 4, l15 = lane & 15;
    int wm = (wave >> 1) * (16 * MF), wn = (wave & 1) * 32;
    int m0 = blockIdx.y * BM, n0 = blockIdx.x * 64;

    f32x4 acc[MF][2];
    #pragma unroll
    for (int i = 0; i < MF; ++i) {
        acc[i][0] = (f32x4){0.f, 0.f, 0.f, 0.f};
        acc[i][1] = (f32x4){0.f, 0.f, 0.f, 0.f};
    }

    for (int k0 = 0; k0 < K; k0 += 64) {
        #pragma unroll
        for (int p = 0; p < MF * 2; ++p) {
            int t = tid + p * 256;
            int r = t >> 4, c4 = (t & 15) << 2;
            float4 v = *(const float4*)(A + (size_t)(m0 + r) * lda + k0 + c4);
            *(ushort4*)&As[r][c4] =
                make_ushort4(f2bfu(v.x), f2bfu(v.y), f2bfu(v.z), f2bfu(v.w));
        }
        #pragma unroll
        for (int p = 0; p < 4; ++p) {
            int t = tid + p * 256;
            int r = t >> 4, c4 = (t & 15) << 2;
            float4 v = *(const float4*)(W + (size_t)(n0 + r) * K + k0 + c4);
            *(ushort4*)&Ws[r][c4] =
                make_ushort4(f2bfu(v.x), f2bfu(v.y), f2bfu(v.z), f2bfu(v.w));
        }
        __syncthreads();
        #pragma unroll
        for (int ks = 0; ks < 2; ++ks) {
            short8 b0 = *(const short8*)&Ws[wn + l15][ks * 32 + quad * 8];
            short8 b1 = *(const short8*)&Ws[wn + 16 + l15][ks * 32 + quad * 8];
            #pragma unroll
            for (int i = 0; i < MF; ++i) {
                short8 a = *(const short8*)&As[wm + i * 16 + l15][ks * 32 + quad * 8];
                acc[i][0] = __builtin_amdgcn_mfma_f32_16x16x32_bf16(a, b0, acc[i][0], 0, 0, 0);
                acc[i][1] = __builtin_amdgcn_mfma_f32_16x16x32_bf16(a, b1, acc[i][1], 0, 0, 0);
            }
        }
        __syncthreads();
    }

    float bj0 = bias ? bias[n0 + wn + l15] : 0.f;
    float bj1 = bias ? bias[n0 + wn + 16 + l15] : 0.f;
    #pragma unroll
    for (int i = 0; i < MF; ++i) {
        #pragma unroll
        for (int r = 0; r < 4; ++r) {
            int m = m0 + wm + i * 16 + quad * 4 + r;
            C[(size_t)m * N + n0 + wn + l15]      = acc[i][0][r] + bj0;
            C[(size_t)m * N + n0 + wn + 16 + l15] = acc[i][1][r] + bj1;
        }
    }
}

// ---------------------------------------------------------------------------
// fp32 linear (small/precision-sensitive GEMMs): Cout = act(A@W^T + bias)
// 16x16 threads, micro-tile TM x TN; BM=16*TM, BN=16*TN.
// ---------------------------------------------------------------------------
template <int BM, int BN, int TM, int TN>
__global__ __launch_bounds__(256)
void linear_kernel(const float* __restrict__ A, int lda,
                   const float* __restrict__ W, const float* __restrict__ bias,
                   float* __restrict__ Cout,
                   int M, int N, int K, int act)
{
    __shared__ __align__(16) float As[16][BM + 4];
    __shared__ __align__(16) float Ws[16][BN + 4];
    int tid = threadIdx.x;
    int tx = tid & 15, ty = tid >> 4;
    int m0 = blockIdx.y * BM, n0 = blockIdx.x * BN;

    float acc[TM][TN];
    #pragma unroll
    for (int i = 0; i < TM; ++i)
        #pragma unroll
        for (int j = 0; j < TN; ++j) acc[i][j] = 0.f;

    for (int k0 = 0; k0 < K; k0 += 16) {
        for (int t = tid; t < 4 * BM; t += 256) {
            int r = t >> 2, kk = (t & 3) << 2;
            float4 v = *(const float4*)(A + (size_t)(m0 + r) * lda + (k0 + kk));
            As[kk + 0][r] = v.x; As[kk + 1][r] = v.y;
            As[kk + 2][r] = v.z; As[kk + 3][r] = v.w;
        }
        for (int t = tid; t < 4 * BN; t += 256) {
            int r = t >> 2, kk = (t & 3) << 2;
            float4 v = make_float4(0.f, 0.f, 0.f, 0.f);
            if (n0 + r < N)
                v = *(const float4*)(W + (size_t)(n0 + r) * K + (k0 + kk));
            Ws[kk + 0][r] = v.x; Ws[kk + 1][r] = v.y;
            Ws[kk + 2][r] = v.z; Ws[kk + 3][r] = v.w;
        }
        __syncthreads();
        #pragma unroll
        for (int kk = 0; kk < 16; ++kk) {
            float a[TM], bb[TN];
            #pragma unroll
            for (int i = 0; i < TM; i += 4)
                *(float4*)&a[i] = *(const float4*)&As[kk][ty * TM + i];
            #pragma unroll
            for (int j = 0; j < TN; j += 4)
                *(float4*)&bb[j] = *(const float4*)&Ws[kk][tx * TN + j];
            #pragma unroll
            for (int i = 0; i < TM; ++i)
                #pragma unroll
                for (int j = 0; j < TN; ++j)
                    acc[i][j] += a[i] * bb[j];
        }
        __syncthreads();
    }

    #pragma unroll
    for (int i = 0; i < TM; ++i) {
        int m = m0 + ty * TM + i;
        #pragma unroll
        for (int j = 0; j < TN; ++j) {
            int n = n0 + tx * TN + j;
            if (n < N) {
                float v = acc[i][j];
                if (bias) v += bias[n];
                if (act == 1) v = (v > 30.f) ? v : log1pf(expf(v));
                Cout[(size_t)m * N + n] = v;
            }
        }
    }
}

// ---------------------------------------------------------------------------
// MFMA flash cross-attention (unchanged from R3).
// ---------------------------------------------------------------------------
__global__ __launch_bounds__(256)
void attn_mfma_kernel(const float* __restrict__ Q, const float* __restrict__ K,
                      const float* __restrict__ V, float* __restrict__ O)
{
    __shared__ unsigned short qs[16][72];
    __shared__ unsigned short pb[16][72];
    __shared__ unsigned short vt[64][72];
    __shared__ float wred[4][16];
    __shared__ float wsum[4][16];
    __shared__ float mrun[16];
    __shared__ float lrun[16];

    int qt = blockIdx.x, h = blockIdx.y, b = blockIdx.z;
    int tid  = threadIdx.x;
    int wave = tid >> 6, lane = tid & 63;
    int quad = lane >> 4, l15 = lane & 15;
    size_t rowbase = (size_t)b * 1024;
    int q0 = qt * 16;
    const float* Qb = Q + (rowbase + q0) * 256 + h * 64;
    const float* Kb = K + rowbase * 256 + h * 64;
    const float* Vb = V + rowbase * 256 + h * 64;

    {
        int r = tid >> 4, c4 = (tid & 15) * 4;
        float4 v = *(const float4*)(Qb + (size_t)r * 256 + c4);
        qs[r][c4 + 0] = f2bfu(v.x * 0.125f);
        qs[r][c4 + 1] = f2bfu(v.y * 0.125f);
        qs[r][c4 + 2] = f2bfu(v.z * 0.125f);
        qs[r][c4 + 3] = f2bfu(v.w * 0.125f);
    }
    if (tid < 16) { mrun[tid] = -1e30f; lrun[tid] = 0.f; }
    __syncthreads();

    short8 qfrag0 = *(const short8*)&qs[l15][quad * 8];
    short8 qfrag1 = *(const short8*)&qs[l15][quad * 8 + 32];

    f32x4 accO = {0.f, 0.f, 0.f, 0.f};
    float mnew4[4], alpha4[4], psum4[4];

    for (int ch = 0; ch < 16; ++ch) {
        int kc0 = ch * 64;
        {
            int f = tid;
            #pragma unroll
            for (int p = 0; p < 4; ++p, f += 256) {
                int kc = f >> 4, c4 = (f & 15) * 4;
                float4 v = *(const float4*)(Vb + (size_t)(kc0 + kc) * 256 + c4);
                vt[c4 + 0][kc] = f2bfu(v.x);
                vt[c4 + 1][kc] = f2bfu(v.y);
                vt[c4 + 2][kc] = f2bfu(v.z);
                vt[c4 + 3][kc] = f2bfu(v.w);
            }
        }
        f32x4 accS = {0.f, 0.f, 0.f, 0.f};
        {
            int kc = kc0 + wave * 16 + l15;
            const float* kp = Kb + (size_t)kc * 256 + quad * 8;
            #pragma unroll
            for (int ks = 0; ks < 2; ++ks) {
                float4 k0v = *(const float4*)(kp + ks * 32);
                float4 k1v = *(const float4*)(kp + ks * 32 + 4);
                short8 bf;
                bf[0] = (short)f2bfu(k0v.x); bf[1] = (short)f2bfu(k0v.y);
                bf[2] = (short)f2bfu(k0v.z); bf[3] = (short)f2bfu(k0v.w);
                bf[4] = (short)f2bfu(k1v.x); bf[5] = (short)f2bfu(k1v.y);
                bf[6] = (short)f2bfu(k1v.z); bf[7] = (short)f2bfu(k1v.w);
                accS = __builtin_amdgcn_mfma_f32_16x16x32_bf16(
                    ks == 0 ? qfrag0 : qfrag1, bf, accS, 0, 0, 0);
            }
        }
        {
            float m4[4];
            #pragma unroll
            for (int r = 0; r < 4; ++r) {
                float m = accS[r];
                m = fmaxf(m, __shfl_xor(m, 1));
                m = fmaxf(m, __shfl_xor(m, 2));
                m = fmaxf(m, __shfl_xor(m, 4));
                m = fmaxf(m, __shfl_xor(m, 8));
                m4[r] = m;
            }
            if (l15 == 0)
                #pragma unroll
                for (int r = 0; r < 4; ++r) wred[wave][quad * 4 + r] = m4[r];
        }
        __syncthreads();

        #pragma unroll
        for (int r = 0; r < 4; ++r) {
            int row = quad * 4 + r;
            float mrow = fmaxf(fmaxf(wred[0][row], wred[1][row]),
                               fmaxf(wred[2][row], wred[3][row]));
            float mold = mrun[row];
            float mnew = fmaxf(mold, mrow);
            float alpha = expf(mold - mnew);
            float p = expf(accS[r] - mnew);
            pb[row][wave * 16 + l15] = f2bfu(p);
            float ps = p;
            ps += __shfl_xor(ps, 1);
            ps += __shfl_xor(ps, 2);
            ps += __shfl_xor(ps, 4);
            ps += __shfl_xor(ps, 8);
            accO[r] *= alpha;
            mnew4[r] = mnew; alpha4[r] = alpha; psum4[r] = ps;
        }
        if (l15 == 0)
            #pragma unroll
            for (int r = 0; r < 4; ++r) wsum[wave][quad * 4 + r] = psum4[r];
        __syncthreads();

        if (wave == 0 && l15 == 0) {
            #pragma unroll
            for (int r = 0; r < 4; ++r) {
                int row = quad * 4 + r;
                mrun[row] = mnew4[r];
                lrun[row] = lrun[row] * alpha4[r] +
                            wsum[0][row] + wsum[1][row] + wsum[2][row] + wsum[3][row];
            }
        }
        #pragma unroll
        for (int ks = 0; ks < 2; ++ks) {
            short8 a  = *(const short8*)&pb[l15][quad * 8 + ks * 32];
            short8 bv = *(const short8*)&vt[wave * 16 + l15][quad * 8 + ks * 32];
            accO = __builtin_amdgcn_mfma_f32_16x16x32_bf16(a, bv, accO, 0, 0, 0);
        }
        __syncthreads();
    }

    #pragma unroll
    for (int r = 0; r < 4; ++r) {
        int row = quad * 4 + r;
        float o = accO[r] / lrun[row];
        O[(rowbase + q0 + row) * 256 + h * 64 + wave * 16 + l15] = o;
    }
}

// ---------------------------------------------------------------------------
// Criss-cross attention, one block per (b, line, branch).
// ---------------------------------------------------------------------------
__global__ __launch_bounds__(256)
void cca_kernel(const float* __restrict__ QC, const float* __restrict__ KC,
                const float* __restrict__ VC,
                float* __restrict__ OH, float* __restrict__ OV)
{
    int rowid = blockIdx.x;       // 0..31
    int b     = blockIdx.y;
    int vert  = blockIdx.z;
    int base   = vert ? rowid : rowid * 32;
    int stride = vert ? 32 : 1;
    size_t pix0 = (size_t)b * 1024 + base;

    __shared__ float qs[32][65];
    __shared__ float ks[32][65];
    __shared__ float ps[32][33];

    int tid = threadIdx.x;
    for (int i = tid; i < 2048; i += 256) {
        int w = i >> 6, c = i & 63;
        size_t p = pix0 + (size_t)w * stride;
        qs[w][c] = QC[p * 64 + c];
        ks[w][c] = KC[p * 64 + c];
    }
    __syncthreads();

    {
        int wp = tid & 31, wr = tid >> 5;
        #pragma unroll
        for (int g = 0; g < 4; ++g) {
            int w = wr + g * 8;
            float s = 0.f;
            #pragma unroll
            for (int c = 0; c < 64; ++c) s += qs[w][c] * ks[wp][c];
            float mx = s;
            #pragma unroll
            for (int m = 16; m >= 1; m >>= 1) mx = fmaxf(mx, __shfl_xor(mx, m));
            float e = expf(s - mx);
            float sum = e;
            #pragma unroll
            for (int m = 16; m >= 1; m >>= 1) sum += __shfl_xor(sum, m);
            ps[w][wp] = e / sum;
        }
    }
    __syncthreads();

    {
        int c = tid;
        float acc[32];
        #pragma unroll
        for (int w = 0; w < 32; ++w) acc[w] = 0.f;
        for (int wp = 0; wp < 32; ++wp) {
            float vv = VC[(pix0 + (size_t)wp * stride) * 256 + c];
            #pragma unroll
            for (int w = 0; w < 32; ++w) acc[w] += ps[w][wp] * vv;
        }
        float* Oo = vert ? OV : OH;
        for (int w = 0; w < 32; ++w)
            Oo[(pix0 + (size_t)w * stride) * 256 + c] = acc[w];
    }
}

// Out = gamma*(OH+OV) + X
__global__ __launch_bounds__(256)
void combine_kernel(const float* __restrict__ OH, const float* __restrict__ OV,
                    const float* __restrict__ X, const float* __restrict__ gamma,
                    float* __restrict__ Out)
{
    int idx = blockIdx.x * 256 + threadIdx.x;
    float g = gamma[0];
    Out[idx] = g * (OH[idx] + OV[idx]) + X[idx];
}

// ---------------------------------------------------------------------------
// Causal depthwise conv(4) + bias + silu.  XZ: (B,L,1024), u = cols 0..511.
// ---------------------------------------------------------------------------
__global__ __launch_bounds__(256)
void conv_silu_kernel(const float* __restrict__ XZ, const float* __restrict__ cw,
                      const float* __restrict__ cb, float* __restrict__ U)
{
    int idx = blockIdx.x * 256 + threadIdx.x;   // B*L*512 = 4194304
    int d = idx & 511;
    int l = (idx >> 9) & 1023;
    int b = idx >> 19;
    float acc = cb[d];
    #pragma unroll
    for (int j = 0; j < 4; ++j) {
        int ls = l - 3 + j;
        if (ls >= 0)
            acc += XZ[((size_t)(b * 1024 + ls)) * 1024 + d] * cw[d * 4 + j];
    }
    U[idx] = acc / (1.f + expf(-acc));   // silu
}

// ---------------------------------------------------------------------------
// Chunked selective scan (3 passes), see R2.
// ---------------------------------------------------------------------------
#define SCAN_NC 32
#define SCAN_TC 32

__global__ __launch_bounds__(256)
void scan_pass1(const float* __restrict__ DL, const float* __restrict__ U,
                const float* __restrict__ XD, const float* __restrict__ A_log,
                float* __restrict__ Pbuf, float* __restrict__ Sbuf)
{
    int idx = blockIdx.x * 256 + threadIdx.x;   // 8*32*512 = 131072
    int d = idx & 511;
    int c = (idx >> 9) & (SCAN_NC - 1);
    int b = idx >> 14;

    float A[16];
    #pragma unroll
    for (int g = 0; g < 4; ++g)
        *(float4*)&A[g * 4] = *(const float4*)(A_log + d * 16 + g * 4);
    #pragma unroll
    for (int n = 0; n < 16; ++n) A[n] = -expf(A[n]);

    float P[16], S[16];
    #pragma unroll
    for (int n = 0; n < 16; ++n) { P[n] = 1.f; S[n] = 0.f; }

    const float* dl = DL + ((size_t)b * 1024 + c * SCAN_TC) * 512 + d;
    const float* uu = U  + ((size_t)b * 1024 + c * SCAN_TC) * 512 + d;
    const float* xd = XD + (size_t)b * 1024 * 48 + (size_t)(c * SCAN_TC) * 48;

    for (int tt = 0; tt < SCAN_TC; ++tt) {
        float delta = dl[(size_t)tt * 512];
        float u     = uu[(size_t)tt * 512];
        float du = delta * u;
        float Bm[16];
        #pragma unroll
        for (int g = 0; g < 4; ++g)
            *(float4*)&Bm[g * 4] = *(const float4*)(xd + tt * 48 + 16 + g * 4);
        #pragma unroll
        for (int n = 0; n < 16; ++n) {
            float a = expf(delta * A[n]);
            S[n] = a * S[n] + du * Bm[n];
            P[n] *= a;
        }
    }

    size_t off = ((size_t)idx) * 16;
    #pragma unroll
    for (int g = 0; g < 4; ++g) {
        *(float4*)(Pbuf + off + g * 4) = *(const float4*)&P[g * 4];
        *(float4*)(Sbuf + off + g * 4) = *(const float4*)&S[g * 4];
    }
}

__global__ __launch_bounds__(256)
void scan_pass2(const float* __restrict__ Pbuf, float* __restrict__ Sbuf)
{
    int idx = blockIdx.x * 256 + threadIdx.x;   // 8*512*16 = 65536
    int dn = idx & 8191;
    int b  = idx >> 13;

    float h = 0.f;
    #pragma unroll 4
    for (int c = 0; c < SCAN_NC; ++c) {
        size_t off = (((size_t)b * SCAN_NC + c) * 512 * 16) + dn;
        float p = Pbuf[off];
        float s = Sbuf[off];
        Sbuf[off] = h;           // becomes h_in for chunk c
        h = p * h + s;
    }
}

__global__ __launch_bounds__(256)
void scan_pass3(const float* __restrict__ DL, const float* __restrict__ U,
                const float* __restrict__ XD, float* __restrict__ XZ,
                const float* __restrict__ A_log, const float* __restrict__ Dp,
                const float* __restrict__ Sbuf)
{
    int idx = blockIdx.x * 256 + threadIdx.x;   // 131072
    int d = idx & 511;
    int c = (idx >> 9) & (SCAN_NC - 1);
    int b = idx >> 14;

    float A[16], h[16];
    #pragma unroll
    for (int g = 0; g < 4; ++g)
        *(float4*)&A[g * 4] = *(const float4*)(A_log + d * 16 + g * 4);
    #pragma unroll
    for (int n = 0; n < 16; ++n) A[n] = -expf(A[n]);

    size_t soff = ((size_t)idx) * 16;
    #pragma unroll
    for (int g = 0; g < 4; ++g)
        *(float4*)&h[g * 4] = *(const float4*)(Sbuf + soff + g * 4);

    float Dval = Dp[d];

    const float* dl = DL + ((size_t)b * 1024 + c * SCAN_TC) * 512 + d;
    const float* uu = U  + ((size_t)b * 1024 + c * SCAN_TC) * 512 + d;
    const float* xd = XD + (size_t)b * 1024 * 48 + (size_t)(c * SCAN_TC) * 48;
    float* xz = XZ + ((size_t)b * 1024 + c * SCAN_TC) * 1024 + d;

    for (int tt = 0; tt < SCAN_TC; ++tt) {
        float delta = dl[(size_t)tt * 512];
        float u     = uu[(size_t)tt * 512];
        float du = delta * u;
        float Bm[16], Cm[16];
        #pragma unroll
        for (int g = 0; g < 4; ++g) {
            *(float4*)&Bm[g * 4] = *(const float4*)(xd + tt * 48 + 16 + g * 4);
            *(float4*)&Cm[g * 4] = *(const float4*)(xd + tt * 48 + 32 + g * 4);
        }
        float y = 0.f;
        #pragma unroll
        for (int n = 0; n < 16; ++n) {
            float a = expf(delta * A[n]);
            h[n] = a * h[n] + du * Bm[n];
            y += h[n] * Cm[n];
        }
        float z = xz[(size_t)tt * 1024 + 512];
        float out = (y + u * Dval) * (z / (1.f + expf(-z)));
        xz[(size_t)tt * 1024] = out;
    }
}

// ---------------------------------------------------------------------------
extern "C" void kernel_launch(void* const* d_in, const int* in_sizes, int n_in,
                              void* d_out, int out_size, void* d_ws, size_t ws_size,
                              hipStream_t stream)
{
    (void)in_sizes; (void)n_in; (void)out_size; (void)ws_size;
    const float* sam   = (const float*)d_in[0];
    const float* myn   = (const float*)d_in[1];
    const float* wq    = (const float*)d_in[2];
    const float* bq    = (const float*)d_in[3];
    const float* wk    = (const float*)d_in[4];
    const float* bk    = (const float*)d_in[5];
    const float* wv    = (const float*)d_in[6];
    const float* bv    = (const float*)d_in[7];
    const float* wo    = (const float*)d_in[8];
    const float* bo    = (const float*)d_in[9];
    const float* cqw   = (const float*)d_in[10];
    const float* cqb   = (const float*)d_in[11];
    const float* ckw   = (const float*)d_in[12];
    const float* ckb   = (const float*)d_in[13];
    const float* cvw   = (const float*)d_in[14];
    const float* cvb   = (const float*)d_in[15];
    const float* gamma = (const float*)d_in[16];
    const float* to_seq_w   = (const float*)d_in[17];
    const float* to_seq_b   = (const float*)d_in[18];
    const float* in_proj_w  = (const float*)d_in[19];
    const float* conv_w     = (const float*)d_in[20];
    const float* conv_b     = (const float*)d_in[21];
    const float* x_proj_w   = (const float*)d_in[22];
    const float* dt_w       = (const float*)d_in[23];
    const float* dt_b       = (const float*)d_in[24];
    const float* A_log      = (const float*)d_in[25];
    const float* Dp         = (const float*)d_in[26];
    const float* out_proj_w = (const float*)d_in[27];
    const float* from_seq_w = (const float*)d_in[28];
    const float* from_seq_b = (const float*)d_in[29];

    // workspace layout (floats); total ~85.5 MB
    float* ws = (float*)d_ws;
    float* P0 = ws;                         // (B,L,C)  2097152
    float* P1 = ws + (size_t)2097152;       // (B,L,C)  2097152
    float* W0 = ws + (size_t)4194304;       // 8388608  (Q/K/V/O, then XZ)
    float* W1 = ws + (size_t)12582912;      // 4194304  (qc/kc/vc, then U)
    float* W2 = ws + (size_t)16777216;      // 4194304  (OH/OV, T, DL, MO)
    float* W4 = ws + (size_t)20971520;      // 393216   (XD)

    dim3 tb(32, 8, 1);
    transpose_kernel<<<dim3(32, 8, 8), tb, 0, stream>>>(sam, P0, 256, 1024);
    transpose_kernel<<<dim3(32, 8, 8), tb, 0, stream>>>(myn, P1, 256, 1024);

    // MFMA GEMM, BM=64: grid (N/64, 128) -- 512+ blocks
    auto gemmMid = [&](const float* A, int lda, const float* Wp, const float* bias,
                       float* Cout, int N, int K) {
        gemm_mfma_kernel<2><<<dim3(N / 64, 128), 256, 0, stream>>>(
            A, lda, Wp, bias, Cout, N, K);
    };
    // MFMA GEMM, BM=128 (for N=1024): grid (16, 64) = 1024 blocks
    auto gemmWide = [&](const float* A, int lda, const float* Wp, const float* bias,
                        float* Cout, int N, int K) {
        gemm_mfma_kernel<4><<<dim3(N / 64, 64), 256, 0, stream>>>(
            A, lda, Wp, bias, Cout, N, K);
    };
    // fp32 linear, N <= 64
    auto linSmall = [&](const float* A, int lda, const float* Wp, const float* bias,
                        float* Cout, int N, int K, int act) {
        linear_kernel<64, 64, 4, 4><<<dim3(1, 128), 256, 0, stream>>>(
            A, lda, Wp, bias, Cout, 8192, N, K, act);
    };
    // fp32 linear, mid N
    auto linMid = [&](const float* A, int lda, const float* Wp, const float* bias,
                      float* Cout, int N, int K, int act) {
        linear_kernel<128, 64, 8, 4><<<dim3((N + 63) / 64, 64), 256, 0, stream>>>(
            A, lda, Wp, bias, Cout, 8192, N, K, act);
    };

    // ---- cross attention ----
    float* Qb = W0;
    float* Kb = W0 + 2097152;
    float* Vb = W0 + 4194304;
    float* Ob = W0 + 6291456;
    gemmMid(P0, 256, wq, bq, Qb, 256, 256);
    gemmMid(P1, 256, wk, bk, Kb, 256, 256);
    gemmMid(P1, 256, wv, bv, Vb, 256, 256);
    attn_mfma_kernel<<<dim3(64, 4, 8), 256, 0, stream>>>(Qb, Kb, Vb, Ob);
    gemmMid(Ob, 256, wo, bo, P0, 256, 256);        // fusion -> P0

    // ---- criss-cross attention ----
    float* QC = W1;
    float* KC = W1 + 524288;
    float* VC = W1 + 1048576;
    linSmall(P0, 256, cqw, cqb, QC, 64, 256, 0);
    linSmall(P0, 256, ckw, ckb, KC, 64, 256, 0);
    gemmMid (P0, 256, cvw, cvb, VC, 256, 256);
    float* OH = W2;
    float* OV = W2 + 2097152;
    cca_kernel<<<dim3(32, 8, 2), 256, 0, stream>>>(QC, KC, VC, OH, OV);
    combine_kernel<<<8192, 256, 0, stream>>>(OH, OV, P0, gamma, P1); // spatial -> P1

    // ---- 2x mamba blocks ----
    for (int i = 0; i < 2; ++i) {
        const float* Sin = (i == 0) ? P1 : P0;
        float* Sout      = (i == 0) ? P0 : P1;
        float* T = W2;
        gemmMid(Sin, 256, to_seq_w + (size_t)i * 65536, to_seq_b + i * 256, T, 256, 256);
        gemmWide(T, 256, in_proj_w + (size_t)i * 262144, nullptr, W0, 1024, 256);   // XZ
        conv_silu_kernel<<<16384, 256, 0, stream>>>(W0, conv_w + (size_t)i * 2048,
                                                    conv_b + i * 512, W1);          // U
        linSmall(W1, 512, x_proj_w + (size_t)i * 24576, nullptr, W4, 48, 512, 0);   // XD
        linMid(W4, 48, dt_w + (size_t)i * 8192, dt_b + i * 512, W2, 512, 16, 1);    // DL (softplus)

        // chunked scan: Pbuf = Sout region (free until from_seq), Sbuf = d_out
        float* Pbuf = Sout;
        float* Sbuf = (float*)d_out;
        scan_pass1<<<512, 256, 0, stream>>>(W2, W1, W4,
                                            A_log + (size_t)i * 8192, Pbuf, Sbuf);
        scan_pass2<<<256, 256, 0, stream>>>(Pbuf, Sbuf);
        scan_pass3<<<512, 256, 0, stream>>>(W2, W1, W4, W0,
                                            A_log + (size_t)i * 8192, Dp + i * 512,
                                            Sbuf);

        gemmMid(W0, 1024, out_proj_w + (size_t)i * 131072, nullptr, W2, 256, 512);  // MO
        gemmMid(W2, 256, from_seq_w + (size_t)i * 65536, from_seq_b + i * 256, Sout, 256, 256);
    }

    // final (B,L,C) -> (B,C,L)
    transpose_kernel<<<dim3(8, 32, 8), tb, 0, stream>>>(P1, (float*)d_out, 1024, 256);
}

// Round 5
// 788.214 us; speedup vs baseline: 4.3550x; 1.1892x over previous
//
#include <hip/hip_runtime.h>
#include <math.h>

// Problem constants
// B=8, C=256, H=32, W=32, L=1024, HEADS=4 (dh=64), IC=64,
// D_INNER=512, DT_RANK=16, D_STATE=16, D_CONV=4, DEPTH=2, M=B*L=8192

typedef short short8 __attribute__((ext_vector_type(8)));
typedef float f32x4  __attribute__((ext_vector_type(4)));

__device__ __forceinline__ unsigned short f2bfu(float x)
{
    union { float f; unsigned int u; } c; c.f = x;
    unsigned int u = c.u + 0x7FFFu + ((c.u >> 16) & 1u);
    return (unsigned short)(u >> 16);
}

// ---------------------------------------------------------------------------
// Weight pre-pack: 21 chunks of 65536 fp32 -> bf16 into Wb.
// ---------------------------------------------------------------------------
struct PackTab { const float* src[21]; };

__global__ __launch_bounds__(256)
void pack_weights_kernel(PackTab tab, unsigned short* __restrict__ dst)
{
    int cid = blockIdx.x >> 6;          // 64 blocks per chunk (1024 elems each)
    int sub = blockIdx.x & 63;
    int off = sub * 1024 + threadIdx.x * 4;
    const float* s = tab.src[cid];
    float4 v = *(const float4*)(s + off);
    *(ushort4*)(dst + (size_t)cid * 65536 + off) =
        make_ushort4(f2bfu(v.x), f2bfu(v.y), f2bfu(v.z), f2bfu(v.w));
}

// ---------------------------------------------------------------------------
// Batched transpose (Bn,R,S)->(Bn,S,R); fp32 out and/or bf16 out (nullable)
// ---------------------------------------------------------------------------
__global__ __launch_bounds__(256)
void transpose_kernel(const float* __restrict__ in, float* __restrict__ out,
                      unsigned short* __restrict__ outb, int R, int S)
{
    __shared__ float tile[32][33];
    int b  = blockIdx.z;
    int s0 = blockIdx.x * 32, r0 = blockIdx.y * 32;
    const float* inb = in + (size_t)b * R * S;
    int tx = threadIdx.x, ty = threadIdx.y;  // 32 x 8
    #pragma unroll
    for (int j = 0; j < 32; j += 8)
        tile[ty + j][tx] = inb[(size_t)(r0 + ty + j) * S + (s0 + tx)];
    __syncthreads();
    #pragma unroll
    for (int j = 0; j < 32; j += 8) {
        float v = tile[tx][ty + j];
        size_t o = (size_t)b * R * S + (size_t)(s0 + ty + j) * R + (r0 + tx);
        if (out)  out[o]  = v;
        if (outb) outb[o] = f2bfu(v);
    }
}

// ---------------------------------------------------------------------------
// V^T pack: Vb bf16 (B,L,256) -> VT bf16 (B*4, 64, 1024) per (b,h)
// ---------------------------------------------------------------------------
__global__ __launch_bounds__(256)
void pack_vt_kernel(const unsigned short* __restrict__ Vb,
                    unsigned short* __restrict__ VT)
{
    __shared__ unsigned short t[32][33];
    int kc0 = blockIdx.x * 32, d0 = blockIdx.y * 32, bh = blockIdx.z;
    int b = bh >> 2, h = bh & 3;
    int tx = threadIdx.x, ty = threadIdx.y;
    #pragma unroll
    for (int j = 0; j < 32; j += 8)
        t[ty + j][tx] = Vb[(size_t)(b * 1024 + kc0 + ty + j) * 256 + h * 64 + d0 + tx];
    __syncthreads();
    #pragma unroll
    for (int j = 0; j < 32; j += 8)
        VT[(size_t)bh * 65536 + (size_t)(d0 + ty + j) * 1024 + kc0 + tx] = t[tx][ty + j];
}

// ---------------------------------------------------------------------------
// MFMA bf16 GEMM, all-bf16 operands: C = A(bf16,lda) @ W(bf16,NxK)^T + bias
// Outputs: C fp32 (nullable) and/or Cb bf16 (nullable), both stride N.
// BM = 32*MF, BN = 64, K % 64 == 0, lda % 8 == 0.
// ---------------------------------------------------------------------------
template <int MF>
__global__ __launch_bounds__(256)
void gemm_bf16_kernel(const unsigned short* __restrict__ A, int lda,
                      const unsigned short* __restrict__ W,
                      const float* __restrict__ bias,
                      float* __restrict__ C, unsigned short* __restrict__ Cb,
                      int N, int K)
{
    constexpr int BM = 32 * MF;
    __shared__ unsigned short As[BM][72];
    __shared__ unsigned short Ws[64][72];
    int tid = threadIdx.x;
    int wave = tid >> 6, lane = tid & 63;
    int quad = lane >> 4, l15 = lane & 15;
    int wm = (wave >> 1) * (16 * MF), wn = (wave & 1) * 32;
    int m0 = blockIdx.y * BM, n0 = blockIdx.x * 64;

    f32x4 acc[MF][2];
    #pragma unroll
    for (int i = 0; i < MF; ++i) {
        acc[i][0] = (f32x4){0.f, 0.f, 0.f, 0.f};
        acc[i][1] = (f32x4){0.f, 0.f, 0.f, 0.f};
    }

    for (int k0 = 0; k0 < K; k0 += 64) {
        #pragma unroll
        for (int p = 0; p < MF; ++p) {              // BM/32 iters, 32 rows each
            int t = tid + p * 256;
            int r = t >> 3, c8 = (t & 7) * 8;
            *(short8*)&As[r][c8] =
                *(const short8*)(A + (size_t)(m0 + r) * lda + k0 + c8);
        }
        #pragma unroll
        for (int p = 0; p < 2; ++p) {
            int t = tid + p * 256;
            int r = t >> 3, c8 = (t & 7) * 8;
            *(short8*)&Ws[r][c8] =
                *(const short8*)(W + (size_t)(n0 + r) * K + k0 + c8);
        }
        __syncthreads();
        #pragma unroll
        for (int ks = 0; ks < 2; ++ks) {
            short8 b0 = *(const short8*)&Ws[wn + l15][ks * 32 + quad * 8];
            short8 b1 = *(const short8*)&Ws[wn + 16 + l15][ks * 32 + quad * 8];
            #pragma unroll
            for (int i = 0; i < MF; ++i) {
                short8 a = *(const short8*)&As[wm + i * 16 + l15][ks * 32 + quad * 8];
                acc[i][0] = __builtin_amdgcn_mfma_f32_16x16x32_bf16(a, b0, acc[i][0], 0, 0, 0);
                acc[i][1] = __builtin_amdgcn_mfma_f32_16x16x32_bf16(a, b1, acc[i][1], 0, 0, 0);
            }
        }
        __syncthreads();
    }

    float bj0 = bias ? bias[n0 + wn + l15] : 0.f;
    float bj1 = bias ? bias[n0 + wn + 16 + l15] : 0.f;
    #pragma unroll
    for (int i = 0; i < MF; ++i) {
        #pragma unroll
        for (int r = 0; r < 4; ++r) {
            int m = m0 + wm + i * 16 + quad * 4 + r;
            float v0 = acc[i][0][r] + bj0;
            float v1 = acc[i][1][r] + bj1;
            size_t o0 = (size_t)m * N + n0 + wn + l15;
            size_t o1 = o0 + 16;
            if (C)  { C[o0] = v0;  C[o1] = v1; }
            if (Cb) { Cb[o0] = f2bfu(v0); Cb[o1] = f2bfu(v1); }
        }
    }
}

// ---------------------------------------------------------------------------
// fp32 linear (small/precision-sensitive): Cout = act(A@W^T + bias)
// ---------------------------------------------------------------------------
template <int BM, int BN, int TM, int TN>
__global__ __launch_bounds__(256)
void linear_kernel(const float* __restrict__ A, int lda,
                   const float* __restrict__ W, const float* __restrict__ bias,
                   float* __restrict__ Cout,
                   int M, int N, int K, int act)
{
    __shared__ __align__(16) float As[16][BM + 4];
    __shared__ __align__(16) float Ws[16][BN + 4];
    int tid = threadIdx.x;
    int tx = tid & 15, ty = tid >> 4;
    int m0 = blockIdx.y * BM, n0 = blockIdx.x * BN;

    float acc[TM][TN];
    #pragma unroll
    for (int i = 0; i < TM; ++i)
        #pragma unroll
        for (int j = 0; j < TN; ++j) acc[i][j] = 0.f;

    for (int k0 = 0; k0 < K; k0 += 16) {
        for (int t = tid; t < 4 * BM; t += 256) {
            int r = t >> 2, kk = (t & 3) << 2;
            float4 v = *(const float4*)(A + (size_t)(m0 + r) * lda + (k0 + kk));
            As[kk + 0][r] = v.x; As[kk + 1][r] = v.y;
            As[kk + 2][r] = v.z; As[kk + 3][r] = v.w;
        }
        for (int t = tid; t < 4 * BN; t += 256) {
            int r = t >> 2, kk = (t & 3) << 2;
            float4 v = make_float4(0.f, 0.f, 0.f, 0.f);
            if (n0 + r < N)
                v = *(const float4*)(W + (size_t)(n0 + r) * K + (k0 + kk));
            Ws[kk + 0][r] = v.x; Ws[kk + 1][r] = v.y;
            Ws[kk + 2][r] = v.z; Ws[kk + 3][r] = v.w;
        }
        __syncthreads();
        #pragma unroll
        for (int kk = 0; kk < 16; ++kk) {
            float a[TM], bb[TN];
            #pragma unroll
            for (int i = 0; i < TM; i += 4)
                *(float4*)&a[i] = *(const float4*)&As[kk][ty * TM + i];
            #pragma unroll
            for (int j = 0; j < TN; j += 4)
                *(float4*)&bb[j] = *(const float4*)&Ws[kk][tx * TN + j];
            #pragma unroll
            for (int i = 0; i < TM; ++i)
                #pragma unroll
                for (int j = 0; j < TN; ++j)
                    acc[i][j] += a[i] * bb[j];
        }
        __syncthreads();
    }

    #pragma unroll
    for (int i = 0; i < TM; ++i) {
        int m = m0 + ty * TM + i;
        #pragma unroll
        for (int j = 0; j < TN; ++j) {
            int n = n0 + tx * TN + j;
            if (n < N) {
                float v = acc[i][j];
                if (bias) v += bias[n];
                if (act == 1) v = (v > 30.f) ? v : log1pf(expf(v));
                Cout[(size_t)m * N + n] = v;
            }
        }
    }
}

// ---------------------------------------------------------------------------
// Flash cross-attention v2: all-bf16 operands, barrier-free K-loop.
// Block = (qt64, h, b), 4 waves; wave owns 16 q rows with private softmax
// state and private LDS P buffer. S scaled by 0.125 post-MFMA.
// ---------------------------------------------------------------------------
__global__ __launch_bounds__(256)
void attn_mfma2_kernel(const unsigned short* __restrict__ Qb,
                       const unsigned short* __restrict__ Kb,
                       const unsigned short* __restrict__ VT,
                       unsigned short* __restrict__ Ob)
{
    __shared__ unsigned short pb[4][16][40];
    int qt = blockIdx.x, h = blockIdx.y, b = blockIdx.z;
    int tid = threadIdx.x;
    int wave = tid >> 6, lane = tid & 63;
    int quad = lane >> 4, l15 = lane & 15;
    size_t rowbase = (size_t)b * 1024;
    int qbase = qt * 64 + wave * 16;

    const unsigned short* Qrow = Qb + (rowbase + qbase + l15) * 256 + h * 64;
    short8 qf0 = *(const short8*)(Qrow + quad * 8);
    short8 qf1 = *(const short8*)(Qrow + 32 + quad * 8);
    const unsigned short* Kh  = Kb + rowbase * 256 + h * 64;
    const unsigned short* VTh = VT + (size_t)(b * 4 + h) * 65536;

    f32x4 accO[4];
    #pragma unroll
    for (int g = 0; g < 4; ++g) accO[g] = (f32x4){0.f, 0.f, 0.f, 0.f};
    float mrun[4] = {-1e30f, -1e30f, -1e30f, -1e30f};
    float lrun[4] = {0.f, 0.f, 0.f, 0.f};

    for (int ch = 0; ch < 32; ++ch) {
        int kc0 = ch * 32;
        const unsigned short* kp0 = Kh + (size_t)(kc0 + l15) * 256 + quad * 8;
        const unsigned short* kp1 = kp0 + 16 * 256;
        f32x4 s0 = (f32x4){0.f, 0.f, 0.f, 0.f};
        f32x4 s1 = (f32x4){0.f, 0.f, 0.f, 0.f};
        s0 = __builtin_amdgcn_mfma_f32_16x16x32_bf16(qf0, *(const short8*)kp0, s0, 0, 0, 0);
        s0 = __builtin_amdgcn_mfma_f32_16x16x32_bf16(qf1, *(const short8*)(kp0 + 32), s0, 0, 0, 0);
        s1 = __builtin_amdgcn_mfma_f32_16x16x32_bf16(qf0, *(const short8*)kp1, s1, 0, 0, 0);
        s1 = __builtin_amdgcn_mfma_f32_16x16x32_bf16(qf1, *(const short8*)(kp1 + 32), s1, 0, 0, 0);

        float alpha4[4];
        #pragma unroll
        for (int r = 0; r < 4; ++r) {
            float v0 = s0[r] * 0.125f, v1 = s1[r] * 0.125f;
            float mm = fmaxf(v0, v1);
            mm = fmaxf(mm, __shfl_xor(mm, 1));
            mm = fmaxf(mm, __shfl_xor(mm, 2));
            mm = fmaxf(mm, __shfl_xor(mm, 4));
            mm = fmaxf(mm, __shfl_xor(mm, 8));
            float mnew = fmaxf(mrun[r], mm);
            float alpha = expf(mrun[r] - mnew);
            float p0 = expf(v0 - mnew);
            float p1 = expf(v1 - mnew);
            int row = quad * 4 + r;
            pb[wave][row][l15]      = f2bfu(p0);
            pb[wave][row][16 + l15] = f2bfu(p1);
            float ps = p0 + p1;
            ps += __shfl_xor(ps, 1);
            ps += __shfl_xor(ps, 2);
            ps += __shfl_xor(ps, 4);
            ps += __shfl_xor(ps, 8);
            lrun[r] = lrun[r] * alpha + ps;
            mrun[r] = mnew;
            alpha4[r] = alpha;
        }
        #pragma unroll
        for (int g = 0; g < 4; ++g)
            #pragma unroll
            for (int r = 0; r < 4; ++r) accO[g][r] *= alpha4[r];

        short8 a = *(const short8*)&pb[wave][l15][quad * 8];
        #pragma unroll
        for (int g = 0; g < 4; ++g) {
            short8 bv = *(const short8*)(VTh + (size_t)(g * 16 + l15) * 1024 + kc0 + quad * 8);
            accO[g] = __builtin_amdgcn_mfma_f32_16x16x32_bf16(a, bv, accO[g], 0, 0, 0);
        }
    }

    #pragma unroll
    for (int r = 0; r < 4; ++r) {
        int row = qbase + quad * 4 + r;
        float inv = 1.f / lrun[r];
        #pragma unroll
        for (int g = 0; g < 4; ++g)
            Ob[(rowbase + row) * 256 + h * 64 + g * 16 + l15] = f2bfu(accO[g][r] * inv);
    }
}

// ---------------------------------------------------------------------------
// Criss-cross attention (fp32, unchanged).
// ---------------------------------------------------------------------------
__global__ __launch_bounds__(256)
void cca_kernel(const float* __restrict__ QC, const float* __restrict__ KC,
                const float* __restrict__ VC,
                float* __restrict__ OH, float* __restrict__ OV)
{
    int rowid = blockIdx.x;
    int b     = blockIdx.y;
    int vert  = blockIdx.z;
    int base   = vert ? rowid : rowid * 32;
    int stride = vert ? 32 : 1;
    size_t pix0 = (size_t)b * 1024 + base;

    __shared__ float qs[32][65];
    __shared__ float ks[32][65];
    __shared__ float ps[32][33];

    int tid = threadIdx.x;
    for (int i = tid; i < 2048; i += 256) {
        int w = i >> 6, c = i & 63;
        size_t p = pix0 + (size_t)w * stride;
        qs[w][c] = QC[p * 64 + c];
        ks[w][c] = KC[p * 64 + c];
    }
    __syncthreads();

    {
        int wp = tid & 31, wr = tid >> 5;
        #pragma unroll
        for (int g = 0; g < 4; ++g) {
            int w = wr + g * 8;
            float s = 0.f;
            #pragma unroll
            for (int c = 0; c < 64; ++c) s += qs[w][c] * ks[wp][c];
            float mx = s;
            #pragma unroll
            for (int m = 16; m >= 1; m >>= 1) mx = fmaxf(mx, __shfl_xor(mx, m));
            float e = expf(s - mx);
            float sum = e;
            #pragma unroll
            for (int m = 16; m >= 1; m >>= 1) sum += __shfl_xor(sum, m);
            ps[w][wp] = e / sum;
        }
    }
    __syncthreads();

    {
        int c = tid;
        float acc[32];
        #pragma unroll
        for (int w = 0; w < 32; ++w) acc[w] = 0.f;
        for (int wp = 0; wp < 32; ++wp) {
            float vv = VC[(pix0 + (size_t)wp * stride) * 256 + c];
            #pragma unroll
            for (int w = 0; w < 32; ++w) acc[w] += ps[w][wp] * vv;
        }
        float* Oo = vert ? OV : OH;
        for (int w = 0; w < 32; ++w)
            Oo[(pix0 + (size_t)w * stride) * 256 + c] = acc[w];
    }
}

// Out = gamma*(OH+OV) + X   (fp32 + bf16 shadow)
__global__ __launch_bounds__(256)
void combine_kernel(const float* __restrict__ OH, const float* __restrict__ OV,
                    const float* __restrict__ X, const float* __restrict__ gamma,
                    float* __restrict__ Out, unsigned short* __restrict__ Outb)
{
    int idx = blockIdx.x * 256 + threadIdx.x;
    float g = gamma[0];
    float v = g * (OH[idx] + OV[idx]) + X[idx];
    Out[idx] = v;
    Outb[idx] = f2bfu(v);
}

// ---------------------------------------------------------------------------
// Causal depthwise conv(4) + bias + silu.  XZ: (B,L,1024), u = cols 0..511.
// ---------------------------------------------------------------------------
__global__ __launch_bounds__(256)
void conv_silu_kernel(const float* __restrict__ XZ, const float* __restrict__ cw,
                      const float* __restrict__ cb, float* __restrict__ U)
{
    int idx = blockIdx.x * 256 + threadIdx.x;
    int d = idx & 511;
    int l = (idx >> 9) & 1023;
    int b = idx >> 19;
    float acc = cb[d];
    #pragma unroll
    for (int j = 0; j < 4; ++j) {
        int ls = l - 3 + j;
        if (ls >= 0)
            acc += XZ[((size_t)(b * 1024 + ls)) * 1024 + d] * cw[d * 4 + j];
    }
    U[idx] = acc / (1.f + expf(-acc));
}

// ---------------------------------------------------------------------------
// Chunked selective scan, dt-projection fused (delta computed in-thread).
// ---------------------------------------------------------------------------
#define SCAN_NC 32
#define SCAN_TC 32

__device__ __forceinline__ float softplusf(float x)
{
    return (x > 30.f) ? x : log1pf(expf(x));
}

__global__ __launch_bounds__(256)
void scan_pass1(const float* __restrict__ U, const float* __restrict__ XD,
                const float* __restrict__ A_log,
                const float* __restrict__ dtw, const float* __restrict__ dtb,
                float* __restrict__ Pbuf, float* __restrict__ Sbuf)
{
    int idx = blockIdx.x * 256 + threadIdx.x;   // 8*32*512 = 131072
    int d = idx & 511;
    int c = (idx >> 9) & (SCAN_NC - 1);
    int b = idx >> 14;

    float A[16], dw[16];
    #pragma unroll
    for (int g = 0; g < 4; ++g) {
        *(float4*)&A[g * 4]  = *(const float4*)(A_log + d * 16 + g * 4);
        *(float4*)&dw[g * 4] = *(const float4*)(dtw + d * 16 + g * 4);
    }
    #pragma unroll
    for (int n = 0; n < 16; ++n) A[n] = -expf(A[n]);
    float db = dtb[d];

    float P[16], S[16];
    #pragma unroll
    for (int n = 0; n < 16; ++n) { P[n] = 1.f; S[n] = 0.f; }

    const float* uu = U  + ((size_t)b * 1024 + c * SCAN_TC) * 512 + d;
    const float* xd = XD + (size_t)b * 1024 * 48 + (size_t)(c * SCAN_TC) * 48;

    for (int tt = 0; tt < SCAN_TC; ++tt) {
        float dt[16];
        #pragma unroll
        for (int g = 0; g < 4; ++g)
            *(float4*)&dt[g * 4] = *(const float4*)(xd + tt * 48 + g * 4);
        float dl = db;
        #pragma unroll
        for (int k = 0; k < 16; ++k) dl += dt[k] * dw[k];
        float delta = softplusf(dl);
        float u = uu[(size_t)tt * 512];
        float du = delta * u;
        float Bm[16];
        #pragma unroll
        for (int g = 0; g < 4; ++g)
            *(float4*)&Bm[g * 4] = *(const float4*)(xd + tt * 48 + 16 + g * 4);
        #pragma unroll
        for (int n = 0; n < 16; ++n) {
            float a = expf(delta * A[n]);
            S[n] = a * S[n] + du * Bm[n];
            P[n] *= a;
        }
    }

    size_t off = ((size_t)idx) * 16;
    #pragma unroll
    for (int g = 0; g < 4; ++g) {
        *(float4*)(Pbuf + off + g * 4) = *(const float4*)&P[g * 4];
        *(float4*)(Sbuf + off + g * 4) = *(const float4*)&S[g * 4];
    }
}

__global__ __launch_bounds__(256)
void scan_pass2(const float* __restrict__ Pbuf, float* __restrict__ Sbuf)
{
    int idx = blockIdx.x * 256 + threadIdx.x;   // 65536
    int dn = idx & 8191;
    int b  = idx >> 13;

    float h = 0.f;
    #pragma unroll 4
    for (int c = 0; c < SCAN_NC; ++c) {
        size_t off = (((size_t)b * SCAN_NC + c) * 512 * 16) + dn;
        float p = Pbuf[off];
        float s = Sbuf[off];
        Sbuf[off] = h;
        h = p * h + s;
    }
}

// pass3: replay; epilogue (y + u*Dp)*silu(z) -> Yb bf16 written into the dead
// u-half of XZ reinterpreted as ushorts (row stride 2048 ushorts, cols 0..511)
__global__ __launch_bounds__(256)
void scan_pass3(const float* __restrict__ U, const float* __restrict__ XD,
                float* __restrict__ XZ,
                const float* __restrict__ A_log,
                const float* __restrict__ dtw, const float* __restrict__ dtb,
                const float* __restrict__ Dp, const float* __restrict__ Sbuf)
{
    int idx = blockIdx.x * 256 + threadIdx.x;   // 131072
    int d = idx & 511;
    int c = (idx >> 9) & (SCAN_NC - 1);
    int b = idx >> 14;

    float A[16], dw[16], h[16];
    #pragma unroll
    for (int g = 0; g < 4; ++g) {
        *(float4*)&A[g * 4]  = *(const float4*)(A_log + d * 16 + g * 4);
        *(float4*)&dw[g * 4] = *(const float4*)(dtw + d * 16 + g * 4);
    }
    #pragma unroll
    for (int n = 0; n < 16; ++n) A[n] = -expf(A[n]);
    float db = dtb[d];

    size_t soff = ((size_t)idx) * 16;
    #pragma unroll
    for (int g = 0; g < 4; ++g)
        *(float4*)&h[g * 4] = *(const float4*)(Sbuf + soff + g * 4);

    float Dval = Dp[d];

    const float* uu = U  + ((size_t)b * 1024 + c * SCAN_TC) * 512 + d;
    const float* xd = XD + (size_t)b * 1024 * 48 + (size_t)(c * SCAN_TC) * 48;
    float* xz = XZ + ((size_t)b * 1024 + c * SCAN_TC) * 1024 + d;
    unsigned short* yb = (unsigned short*)(XZ) +
                         ((size_t)b * 1024 + c * SCAN_TC) * 2048 + d;

    for (int tt = 0; tt < SCAN_TC; ++tt) {
        float dt[16];
        #pragma unroll
        for (int g = 0; g < 4; ++g)
            *(float4*)&dt[g * 4] = *(const float4*)(xd + tt * 48 + g * 4);
        float dl = db;
        #pragma unroll
        for (int k = 0; k < 16; ++k) dl += dt[k] * dw[k];
        float delta = softplusf(dl);
        float u = uu[(size_t)tt * 512];
        float du = delta * u;
        float Bm[16], Cm[16];
        #pragma unroll
        for (int g = 0; g < 4; ++g) {
            *(float4*)&Bm[g * 4] = *(const float4*)(xd + tt * 48 + 16 + g * 4);
            *(float4*)&Cm[g * 4] = *(const float4*)(xd + tt * 48 + 32 + g * 4);
        }
        float y = 0.f;
        #pragma unroll
        for (int n = 0; n < 16; ++n) {
            float a = expf(delta * A[n]);
            h[n] = a * h[n] + du * Bm[n];
            y += h[n] * Cm[n];
        }
        float z = xz[(size_t)tt * 1024 + 512];
        float out = (y + u * Dval) * (z / (1.f + expf(-z)));
        yb[(size_t)tt * 2048] = f2bfu(out);
    }
}

// ---------------------------------------------------------------------------
extern "C" void kernel_launch(void* const* d_in, const int* in_sizes, int n_in,
                              void* d_out, int out_size, void* d_ws, size_t ws_size,
                              hipStream_t stream)
{
    (void)in_sizes; (void)n_in; (void)out_size; (void)ws_size;
    const float* sam   = (const float*)d_in[0];
    const float* myn   = (const float*)d_in[1];
    const float* wq    = (const float*)d_in[2];
    const float* bq    = (const float*)d_in[3];
    const float* wk    = (const float*)d_in[4];
    const float* bk    = (const float*)d_in[5];
    const float* wv    = (const float*)d_in[6];
    const float* bv    = (const float*)d_in[7];
    const float* wo    = (const float*)d_in[8];
    const float* bo    = (const float*)d_in[9];
    const float* cqw   = (const float*)d_in[10];
    const float* cqb   = (const float*)d_in[11];
    const float* ckw   = (const float*)d_in[12];
    const float* ckb   = (const float*)d_in[13];
    const float* cvw   = (const float*)d_in[14];
    const float* cvb   = (const float*)d_in[15];
    const float* gamma = (const float*)d_in[16];
    const float* to_seq_w   = (const float*)d_in[17];
    const float* to_seq_b   = (const float*)d_in[18];
    const float* in_proj_w  = (const float*)d_in[19];
    const float* conv_w     = (const float*)d_in[20];
    const float* conv_b     = (const float*)d_in[21];
    const float* x_proj_w   = (const float*)d_in[22];
    const float* dt_w       = (const float*)d_in[23];
    const float* dt_b       = (const float*)d_in[24];
    const float* A_log      = (const float*)d_in[25];
    const float* Dp         = (const float*)d_in[26];
    const float* out_proj_w = (const float*)d_in[27];
    const float* from_seq_w = (const float*)d_in[28];
    const float* from_seq_b = (const float*)d_in[29];

    // ---- workspace segments (floats), total 21,364,736 (~85.5 MB, proven) --
    float* wsf = (float*)d_ws;
    float* SEG_A = wsf;                          // 2,097,152  P0 fp32 / Pbuf d0
    float* SEG_B = wsf + (size_t)2097152;        // 2,097,152  P1 fp32 / Pbuf d1
    float* SEG_C = wsf + (size_t)4194304;        // 8,388,608  attn bf16 / QC,KC / XZ
    float* SEG_D = wsf + (size_t)12582912;       // 4,194,304  P0b,P1b / OH,VC / U
    float* SEG_E = wsf + (size_t)16777216;       // 4,194,304  Wb / Tb,MOb / Snb
    float* SEG_F = wsf + (size_t)20971520;       //   393,216  XD

    // bf16 views
    unsigned short* Wb   = (unsigned short*)SEG_E;              // 1,376,256
    unsigned short* TMb  = (unsigned short*)SEG_E + 1376256;    // 2,097,152 (Tb/MOb)
    unsigned short* Snb  = (unsigned short*)SEG_E + 3473408;    // 2,097,152 (Sinb/Soutb)
    unsigned short* Qbf  = (unsigned short*)SEG_C;              // 2,097,152
    unsigned short* Kbf  = (unsigned short*)SEG_C + 2097152;
    unsigned short* Vbf  = (unsigned short*)SEG_C + 4194304;
    unsigned short* Obf  = (unsigned short*)SEG_C + 6291456;
    unsigned short* P0b  = (unsigned short*)SEG_D;              // 2,097,152
    unsigned short* P1b  = (unsigned short*)SEG_D + 2097152;
    unsigned short* VTb  = (unsigned short*)d_out;              // 2,097,152
    float* P0 = SEG_A;
    float* P1 = SEG_B;
    float* QC = SEG_C;                     // 524,288 floats
    float* KC = SEG_C + 524288;
    float* OH = SEG_D;                     // 2,097,152 floats
    float* VC = SEG_D + 2097152;           // 2,097,152 floats
    float* OV = (float*)d_out;             // 2,097,152 floats (VT dead)
    float* XZ = SEG_C;                     // 8,388,608 floats
    float* Ub = SEG_D;                     // 4,194,304 floats
    float* XD = SEG_F;

    // Wb chunk offsets (shorts)
    const size_t WB_WQ = 0, WB_WK = 65536, WB_WV = 131072, WB_WO = 196608,
                 WB_CV = 262144, WB_D0 = 327680, WB_DSTRIDE = 524288;
    const size_t WB_TOSEQ = 0, WB_INPROJ = 65536, WB_OUTPROJ = 327680,
                 WB_FROMSEQ = 458752;

    // ---- weight pre-pack (21 x 65536) ----
    PackTab tab;
    tab.src[0] = wq; tab.src[1] = wk; tab.src[2] = wv; tab.src[3] = wo;
    tab.src[4] = cvw;
    for (int i = 0; i < 2; ++i) {
        int base = 5 + i * 8;
        tab.src[base + 0] = to_seq_w + (size_t)i * 65536;
        for (int c = 0; c < 4; ++c)
            tab.src[base + 1 + c] = in_proj_w + (size_t)i * 262144 + (size_t)c * 65536;
        for (int c = 0; c < 2; ++c)
            tab.src[base + 5 + c] = out_proj_w + (size_t)i * 131072 + (size_t)c * 65536;
        tab.src[base + 7] = from_seq_w + (size_t)i * 65536;
    }
    pack_weights_kernel<<<1344, 256, 0, stream>>>(tab, Wb);

    dim3 tb(32, 8, 1);
    // inputs (B,C,L) -> (B,L,C) bf16 only
    transpose_kernel<<<dim3(32, 8, 8), tb, 0, stream>>>(sam, nullptr, P0b, 256, 1024);
    transpose_kernel<<<dim3(32, 8, 8), tb, 0, stream>>>(myn, nullptr, P1b, 256, 1024);

    auto gemmMid = [&](const unsigned short* A, int lda, const unsigned short* W,
                       const float* bias, float* C, unsigned short* Cb, int N, int K) {
        gemm_bf16_kernel<2><<<dim3(N / 64, 128), 256, 0, stream>>>(
            A, lda, W, bias, C, Cb, N, K);
    };
    auto gemmWide = [&](const unsigned short* A, int lda, const unsigned short* W,
                        const float* bias, float* C, unsigned short* Cb, int N, int K) {
        gemm_bf16_kernel<4><<<dim3(N / 64, 64), 256, 0, stream>>>(
            A, lda, W, bias, C, Cb, N, K);
    };
    auto linSmall = [&](const float* A, int lda, const float* W, const float* bias,
                        float* Cout, int N, int K, int act) {
        linear_kernel<64, 64, 4, 4><<<dim3(1, 128), 256, 0, stream>>>(
            A, lda, W, bias, Cout, 8192, N, K, act);
    };

    // ---- cross attention ----
    gemmMid(P0b, 256, Wb + WB_WQ, bq, nullptr, Qbf, 256, 256);
    gemmMid(P1b, 256, Wb + WB_WK, bk, nullptr, Kbf, 256, 256);
    gemmMid(P1b, 256, Wb + WB_WV, bv, nullptr, Vbf, 256, 256);
    pack_vt_kernel<<<dim3(32, 2, 32), tb, 0, stream>>>(Vbf, VTb);
    attn_mfma2_kernel<<<dim3(16, 4, 8), 256, 0, stream>>>(Qbf, Kbf, VTb, Obf);
    gemmMid(Obf, 256, Wb + WB_WO, bo, P0, P0b, 256, 256);   // fusion -> P0 (+bf16)

    // ---- criss-cross attention ----
    linSmall(P0, 256, cqw, cqb, QC, 64, 256, 0);
    linSmall(P0, 256, ckw, ckb, KC, 64, 256, 0);
    gemmMid (P0b, 256, Wb + WB_CV, cvb, VC, nullptr, 256, 256);
    cca_kernel<<<dim3(32, 8, 2), 256, 0, stream>>>(QC, KC, VC, OH, OV);
    combine_kernel<<<8192, 256, 0, stream>>>(OH, OV, P0, gamma, P1, Snb);

    // ---- 2x mamba blocks ----
    for (int i = 0; i < 2; ++i) {
        const unsigned short* Wd = Wb + WB_D0 + (size_t)i * WB_DSTRIDE;
        float* Sout = (i == 0) ? P0 : P1;

        gemmMid(Snb, 256, Wd + WB_TOSEQ, to_seq_b + i * 256, nullptr, TMb, 256, 256);
        gemmWide(TMb, 256, Wd + WB_INPROJ, nullptr, XZ, nullptr, 1024, 256);
        conv_silu_kernel<<<16384, 256, 0, stream>>>(XZ, conv_w + (size_t)i * 2048,
                                                    conv_b + i * 512, Ub);
        linSmall(Ub, 512, x_proj_w + (size_t)i * 24576, nullptr, XD, 48, 512, 0);

        float* Pbuf = Sout;
        float* Sbuf = (float*)d_out;
        scan_pass1<<<512, 256, 0, stream>>>(Ub, XD, A_log + (size_t)i * 8192,
                                            dt_w + (size_t)i * 8192, dt_b + i * 512,
                                            Pbuf, Sbuf);
        scan_pass2<<<256, 256, 0, stream>>>(Pbuf, Sbuf);
        scan_pass3<<<512, 256, 0, stream>>>(Ub, XD, XZ,
                                            A_log + (size_t)i * 8192,
                                            dt_w + (size_t)i * 8192, dt_b + i * 512,
                                            Dp + i * 512, Sbuf);

        // out_proj: A = Yb (bf16 in XZ u-half), lda 2048 ushorts
        gemmMid((const unsigned short*)XZ, 2048, Wd + WB_OUTPROJ, nullptr,
                nullptr, TMb, 256, 512);
        gemmMid(TMb, 256, Wd + WB_FROMSEQ, from_seq_b + i * 256, Sout, Snb, 256, 256);
    }

    // final (B,L,C) -> (B,C,L)
    transpose_kernel<<<dim3(8, 32, 8), tb, 0, stream>>>(P1, (float*)d_out, nullptr,
                                                        1024, 256);
}

// Round 6
// 703.565 us; speedup vs baseline: 4.8790x; 1.1203x over previous
//
#include <hip/hip_runtime.h>
#include <math.h>

// Problem constants
// B=8, C=256, H=32, W=32, L=1024, HEADS=4 (dh=64), IC=64,
// D_INNER=512, DT_RANK=16, D_STATE=16, D_CONV=4, DEPTH=2, M=B*L=8192

typedef short short8 __attribute__((ext_vector_type(8)));
typedef float f32x4  __attribute__((ext_vector_type(4)));

__device__ __forceinline__ unsigned short f2bfu(float x)
{
    union { float f; unsigned int u; } c; c.f = x;
    unsigned int u = c.u + 0x7FFFu + ((c.u >> 16) & 1u);
    return (unsigned short)(u >> 16);
}

__device__ __forceinline__ float softplus_fast(float x)
{
    // x > 15: log1p(e^x) == x to fp32 precision
    float e = __expf(x);
    return (x > 15.f) ? x : __logf(1.f + e);
}

// ---------------------------------------------------------------------------
// Weight pre-pack: 21 chunks of 65536 fp32 -> bf16 into Wb.
// ---------------------------------------------------------------------------
struct PackTab { const float* src[21]; };

__global__ __launch_bounds__(256)
void pack_weights_kernel(PackTab tab, unsigned short* __restrict__ dst)
{
    int cid = blockIdx.x >> 6;          // 64 blocks per chunk (1024 elems each)
    int sub = blockIdx.x & 63;
    int off = sub * 1024 + threadIdx.x * 4;
    const float* s = tab.src[cid];
    float4 v = *(const float4*)(s + off);
    *(ushort4*)(dst + (size_t)cid * 65536 + off) =
        make_ushort4(f2bfu(v.x), f2bfu(v.y), f2bfu(v.z), f2bfu(v.w));
}

// ---------------------------------------------------------------------------
// Batched transpose (Bn,R,S)->(Bn,S,R); fp32 out and/or bf16 out (nullable)
// ---------------------------------------------------------------------------
__global__ __launch_bounds__(256)
void transpose_kernel(const float* __restrict__ in, float* __restrict__ out,
                      unsigned short* __restrict__ outb, int R, int S)
{
    __shared__ float tile[32][33];
    int b  = blockIdx.z;
    int s0 = blockIdx.x * 32, r0 = blockIdx.y * 32;
    const float* inb = in + (size_t)b * R * S;
    int tx = threadIdx.x, ty = threadIdx.y;  // 32 x 8
    #pragma unroll
    for (int j = 0; j < 32; j += 8)
        tile[ty + j][tx] = inb[(size_t)(r0 + ty + j) * S + (s0 + tx)];
    __syncthreads();
    #pragma unroll
    for (int j = 0; j < 32; j += 8) {
        float v = tile[tx][ty + j];
        size_t o = (size_t)b * R * S + (size_t)(s0 + ty + j) * R + (r0 + tx);
        if (out)  out[o]  = v;
        if (outb) outb[o] = f2bfu(v);
    }
}

// ---------------------------------------------------------------------------
// V^T pack: Vb bf16 (B,L,256) -> VT bf16 (B*4, 64, 1024) per (b,h)
// ---------------------------------------------------------------------------
__global__ __launch_bounds__(256)
void pack_vt_kernel(const unsigned short* __restrict__ Vb,
                    unsigned short* __restrict__ VT)
{
    __shared__ unsigned short t[32][33];
    int kc0 = blockIdx.x * 32, d0 = blockIdx.y * 32, bh = blockIdx.z;
    int b = bh >> 2, h = bh & 3;
    int tx = threadIdx.x, ty = threadIdx.y;
    #pragma unroll
    for (int j = 0; j < 32; j += 8)
        t[ty + j][tx] = Vb[(size_t)(b * 1024 + kc0 + ty + j) * 256 + h * 64 + d0 + tx];
    __syncthreads();
    #pragma unroll
    for (int j = 0; j < 32; j += 8)
        VT[(size_t)bh * 65536 + (size_t)(d0 + ty + j) * 1024 + kc0 + tx] = t[tx][ty + j];
}

// ---------------------------------------------------------------------------
// MFMA bf16 GEMM, all-bf16 operands: C = A(bf16,lda) @ W(bf16,NxK)^T + bias
// Outputs: C fp32 (nullable) and/or Cb bf16 (nullable), both stride N.
// BM = 32*MF, BN = 64, K % 64 == 0, lda % 8 == 0.
// ---------------------------------------------------------------------------
template <int MF>
__global__ __launch_bounds__(256)
void gemm_bf16_kernel(const unsigned short* __restrict__ A, int lda,
                      const unsigned short* __restrict__ W,
                      const float* __restrict__ bias,
                      float* __restrict__ C, unsigned short* __restrict__ Cb,
                      int N, int K)
{
    constexpr int BM = 32 * MF;
    __shared__ unsigned short As[BM][72];
    __shared__ unsigned short Ws[64][72];
    int tid = threadIdx.x;
    int wave = tid >> 6, lane = tid & 63;
    int quad = lane >> 4, l15 = lane & 15;
    int wm = (wave >> 1) * (16 * MF), wn = (wave & 1) * 32;
    int m0 = blockIdx.y * BM, n0 = blockIdx.x * 64;

    f32x4 acc[MF][2];
    #pragma unroll
    for (int i = 0; i < MF; ++i) {
        acc[i][0] = (f32x4){0.f, 0.f, 0.f, 0.f};
        acc[i][1] = (f32x4){0.f, 0.f, 0.f, 0.f};
    }

    for (int k0 = 0; k0 < K; k0 += 64) {
        #pragma unroll
        for (int p = 0; p < MF; ++p) {              // BM/32 iters, 32 rows each
            int t = tid + p * 256;
            int r = t >> 3, c8 = (t & 7) * 8;
            *(short8*)&As[r][c8] =
                *(const short8*)(A + (size_t)(m0 + r) * lda + k0 + c8);
        }
        #pragma unroll
        for (int p = 0; p < 2; ++p) {
            int t = tid + p * 256;
            int r = t >> 3, c8 = (t & 7) * 8;
            *(short8*)&Ws[r][c8] =
                *(const short8*)(W + (size_t)(n0 + r) * K + k0 + c8);
        }
        __syncthreads();
        #pragma unroll
        for (int ks = 0; ks < 2; ++ks) {
            short8 b0 = *(const short8*)&Ws[wn + l15][ks * 32 + quad * 8];
            short8 b1 = *(const short8*)&Ws[wn + 16 + l15][ks * 32 + quad * 8];
            #pragma unroll
            for (int i = 0; i < MF; ++i) {
                short8 a = *(const short8*)&As[wm + i * 16 + l15][ks * 32 + quad * 8];
                acc[i][0] = __builtin_amdgcn_mfma_f32_16x16x32_bf16(a, b0, acc[i][0], 0, 0, 0);
                acc[i][1] = __builtin_amdgcn_mfma_f32_16x16x32_bf16(a, b1, acc[i][1], 0, 0, 0);
            }
        }
        __syncthreads();
    }

    float bj0 = bias ? bias[n0 + wn + l15] : 0.f;
    float bj1 = bias ? bias[n0 + wn + 16 + l15] : 0.f;
    #pragma unroll
    for (int i = 0; i < MF; ++i) {
        #pragma unroll
        for (int r = 0; r < 4; ++r) {
            int m = m0 + wm + i * 16 + quad * 4 + r;
            float v0 = acc[i][0][r] + bj0;
            float v1 = acc[i][1][r] + bj1;
            size_t o0 = (size_t)m * N + n0 + wn + l15;
            size_t o1 = o0 + 16;
            if (C)  { C[o0] = v0;  C[o1] = v1; }
            if (Cb) { Cb[o0] = f2bfu(v0); Cb[o1] = f2bfu(v1); }
        }
    }
}

// ---------------------------------------------------------------------------
// fp32 linear (small/precision-sensitive): Cout = act(A@W^T + bias)
// ---------------------------------------------------------------------------
template <int BM, int BN, int TM, int TN>
__global__ __launch_bounds__(256)
void linear_kernel(const float* __restrict__ A, int lda,
                   const float* __restrict__ W, const float* __restrict__ bias,
                   float* __restrict__ Cout,
                   int M, int N, int K, int act)
{
    __shared__ __align__(16) float As[16][BM + 4];
    __shared__ __align__(16) float Ws[16][BN + 4];
    int tid = threadIdx.x;
    int tx = tid & 15, ty = tid >> 4;
    int m0 = blockIdx.y * BM, n0 = blockIdx.x * BN;

    float acc[TM][TN];
    #pragma unroll
    for (int i = 0; i < TM; ++i)
        #pragma unroll
        for (int j = 0; j < TN; ++j) acc[i][j] = 0.f;

    for (int k0 = 0; k0 < K; k0 += 16) {
        for (int t = tid; t < 4 * BM; t += 256) {
            int r = t >> 2, kk = (t & 3) << 2;
            float4 v = *(const float4*)(A + (size_t)(m0 + r) * lda + (k0 + kk));
            As[kk + 0][r] = v.x; As[kk + 1][r] = v.y;
            As[kk + 2][r] = v.z; As[kk + 3][r] = v.w;
        }
        for (int t = tid; t < 4 * BN; t += 256) {
            int r = t >> 2, kk = (t & 3) << 2;
            float4 v = make_float4(0.f, 0.f, 0.f, 0.f);
            if (n0 + r < N)
                v = *(const float4*)(W + (size_t)(n0 + r) * K + (k0 + kk));
            Ws[kk + 0][r] = v.x; Ws[kk + 1][r] = v.y;
            Ws[kk + 2][r] = v.z; Ws[kk + 3][r] = v.w;
        }
        __syncthreads();
        #pragma unroll
        for (int kk = 0; kk < 16; ++kk) {
            float a[TM], bb[TN];
            #pragma unroll
            for (int i = 0; i < TM; i += 2) {
                a[i] = As[kk][ty * TM + i];
                a[i + 1] = As[kk][ty * TM + i + 1];
            }
            #pragma unroll
            for (int j = 0; j < TN; j += 4)
                *(float4*)&bb[j] = *(const float4*)&Ws[kk][tx * TN + j];
            #pragma unroll
            for (int i = 0; i < TM; ++i)
                #pragma unroll
                for (int j = 0; j < TN; ++j)
                    acc[i][j] += a[i] * bb[j];
        }
        __syncthreads();
    }

    #pragma unroll
    for (int i = 0; i < TM; ++i) {
        int m = m0 + ty * TM + i;
        #pragma unroll
        for (int j = 0; j < TN; ++j) {
            int n = n0 + tx * TN + j;
            if (n < N) {
                float v = acc[i][j];
                if (bias) v += bias[n];
                if (act == 1) v = softplus_fast(v);
                Cout[(size_t)m * N + n] = v;
            }
        }
    }
}

// ---------------------------------------------------------------------------
// Flash cross-attention v2: all-bf16 operands, barrier-free K-loop.
// ---------------------------------------------------------------------------
__global__ __launch_bounds__(256)
void attn_mfma2_kernel(const unsigned short* __restrict__ Qb,
                       const unsigned short* __restrict__ Kb,
                       const unsigned short* __restrict__ VT,
                       unsigned short* __restrict__ Ob)
{
    __shared__ unsigned short pb[4][16][40];
    int qt = blockIdx.x, h = blockIdx.y, b = blockIdx.z;
    int tid = threadIdx.x;
    int wave = tid >> 6, lane = tid & 63;
    int quad = lane >> 4, l15 = lane & 15;
    size_t rowbase = (size_t)b * 1024;
    int qbase = qt * 64 + wave * 16;

    const unsigned short* Qrow = Qb + (rowbase + qbase + l15) * 256 + h * 64;
    short8 qf0 = *(const short8*)(Qrow + quad * 8);
    short8 qf1 = *(const short8*)(Qrow + 32 + quad * 8);
    const unsigned short* Kh  = Kb + rowbase * 256 + h * 64;
    const unsigned short* VTh = VT + (size_t)(b * 4 + h) * 65536;

    f32x4 accO[4];
    #pragma unroll
    for (int g = 0; g < 4; ++g) accO[g] = (f32x4){0.f, 0.f, 0.f, 0.f};
    float mrun[4] = {-1e30f, -1e30f, -1e30f, -1e30f};
    float lrun[4] = {0.f, 0.f, 0.f, 0.f};

    for (int ch = 0; ch < 32; ++ch) {
        int kc0 = ch * 32;
        const unsigned short* kp0 = Kh + (size_t)(kc0 + l15) * 256 + quad * 8;
        const unsigned short* kp1 = kp0 + 16 * 256;
        f32x4 s0 = (f32x4){0.f, 0.f, 0.f, 0.f};
        f32x4 s1 = (f32x4){0.f, 0.f, 0.f, 0.f};
        s0 = __builtin_amdgcn_mfma_f32_16x16x32_bf16(qf0, *(const short8*)kp0, s0, 0, 0, 0);
        s0 = __builtin_amdgcn_mfma_f32_16x16x32_bf16(qf1, *(const short8*)(kp0 + 32), s0, 0, 0, 0);
        s1 = __builtin_amdgcn_mfma_f32_16x16x32_bf16(qf0, *(const short8*)kp1, s1, 0, 0, 0);
        s1 = __builtin_amdgcn_mfma_f32_16x16x32_bf16(qf1, *(const short8*)(kp1 + 32), s1, 0, 0, 0);

        float alpha4[4];
        #pragma unroll
        for (int r = 0; r < 4; ++r) {
            float v0 = s0[r] * 0.125f, v1 = s1[r] * 0.125f;
            float mm = fmaxf(v0, v1);
            mm = fmaxf(mm, __shfl_xor(mm, 1));
            mm = fmaxf(mm, __shfl_xor(mm, 2));
            mm = fmaxf(mm, __shfl_xor(mm, 4));
            mm = fmaxf(mm, __shfl_xor(mm, 8));
            float mnew = fmaxf(mrun[r], mm);
            float alpha = __expf(mrun[r] - mnew);
            float p0 = __expf(v0 - mnew);
            float p1 = __expf(v1 - mnew);
            int row = quad * 4 + r;
            pb[wave][row][l15]      = f2bfu(p0);
            pb[wave][row][16 + l15] = f2bfu(p1);
            float ps = p0 + p1;
            ps += __shfl_xor(ps, 1);
            ps += __shfl_xor(ps, 2);
            ps += __shfl_xor(ps, 4);
            ps += __shfl_xor(ps, 8);
            lrun[r] = lrun[r] * alpha + ps;
            mrun[r] = mnew;
            alpha4[r] = alpha;
        }
        #pragma unroll
        for (int g = 0; g < 4; ++g)
            #pragma unroll
            for (int r = 0; r < 4; ++r) accO[g][r] *= alpha4[r];

        short8 a = *(const short8*)&pb[wave][l15][quad * 8];
        #pragma unroll
        for (int g = 0; g < 4; ++g) {
            short8 bv = *(const short8*)(VTh + (size_t)(g * 16 + l15) * 1024 + kc0 + quad * 8);
            accO[g] = __builtin_amdgcn_mfma_f32_16x16x32_bf16(a, bv, accO[g], 0, 0, 0);
        }
    }

    #pragma unroll
    for (int r = 0; r < 4; ++r) {
        int row = qbase + quad * 4 + r;
        float inv = 1.f / lrun[r];
        #pragma unroll
        for (int g = 0; g < 4; ++g)
            Ob[(rowbase + row) * 256 + h * 64 + g * 16 + l15] = f2bfu(accO[g][r] * inv);
    }
}

// ---------------------------------------------------------------------------
// Criss-cross attention (fp32).
// ---------------------------------------------------------------------------
__global__ __launch_bounds__(256)
void cca_kernel(const float* __restrict__ QC, const float* __restrict__ KC,
                const float* __restrict__ VC,
                float* __restrict__ OH, float* __restrict__ OV)
{
    int rowid = blockIdx.x;
    int b     = blockIdx.y;
    int vert  = blockIdx.z;
    int base   = vert ? rowid : rowid * 32;
    int stride = vert ? 32 : 1;
    size_t pix0 = (size_t)b * 1024 + base;

    __shared__ float qs[32][65];
    __shared__ float ks[32][65];
    __shared__ float ps[32][33];

    int tid = threadIdx.x;
    for (int i = tid; i < 2048; i += 256) {
        int w = i >> 6, c = i & 63;
        size_t p = pix0 + (size_t)w * stride;
        qs[w][c] = QC[p * 64 + c];
        ks[w][c] = KC[p * 64 + c];
    }
    __syncthreads();

    {
        int wp = tid & 31, wr = tid >> 5;
        #pragma unroll
        for (int g = 0; g < 4; ++g) {
            int w = wr + g * 8;
            float s = 0.f;
            #pragma unroll
            for (int c = 0; c < 64; ++c) s += qs[w][c] * ks[wp][c];
            float mx = s;
            #pragma unroll
            for (int m = 16; m >= 1; m >>= 1) mx = fmaxf(mx, __shfl_xor(mx, m));
            float e = __expf(s - mx);
            float sum = e;
            #pragma unroll
            for (int m = 16; m >= 1; m >>= 1) sum += __shfl_xor(sum, m);
            ps[w][wp] = e / sum;
        }
    }
    __syncthreads();

    {
        int c = tid;
        float acc[32];
        #pragma unroll
        for (int w = 0; w < 32; ++w) acc[w] = 0.f;
        for (int wp = 0; wp < 32; ++wp) {
            float vv = VC[(pix0 + (size_t)wp * stride) * 256 + c];
            #pragma unroll
            for (int w = 0; w < 32; ++w) acc[w] += ps[w][wp] * vv;
        }
        float* Oo = vert ? OV : OH;
        for (int w = 0; w < 32; ++w)
            Oo[(pix0 + (size_t)w * stride) * 256 + c] = acc[w];
    }
}

// Out = gamma*(OH+OV) + X   (fp32 + bf16 shadow)
__global__ __launch_bounds__(256)
void combine_kernel(const float* __restrict__ OH, const float* __restrict__ OV,
                    const float* __restrict__ X, const float* __restrict__ gamma,
                    float* __restrict__ Out, unsigned short* __restrict__ Outb)
{
    int idx = blockIdx.x * 256 + threadIdx.x;
    float g = gamma[0];
    float v = g * (OH[idx] + OV[idx]) + X[idx];
    Out[idx] = v;
    Outb[idx] = f2bfu(v);
}

// ---------------------------------------------------------------------------
// Causal depthwise conv(4) + bias + silu.  XZ: (B,L,1024), u = cols 0..511.
// ---------------------------------------------------------------------------
__global__ __launch_bounds__(256)
void conv_silu_kernel(const float* __restrict__ XZ, const float* __restrict__ cw,
                      const float* __restrict__ cb, float* __restrict__ U)
{
    int idx = blockIdx.x * 256 + threadIdx.x;
    int d = idx & 511;
    int l = (idx >> 9) & 1023;
    int b = idx >> 19;
    float acc = cb[d];
    #pragma unroll
    for (int j = 0; j < 4; ++j) {
        int ls = l - 3 + j;
        if (ls >= 0)
            acc += XZ[((size_t)(b * 1024 + ls)) * 1024 + d] * cw[d * 4 + j];
    }
    U[idx] = acc / (1.f + __expf(-acc));
}

// ---------------------------------------------------------------------------
// Chunked selective scan, dt-projection fused, n-split-2:
// thread = (b, chunk, d, nhalf), 8 states each; 262144 threads.
// idx = (((b*NC + c)*512 + d)*2 + nh)
// ---------------------------------------------------------------------------
#define SCAN_NC 32
#define SCAN_TC 32

__global__ __launch_bounds__(256)
void scan_pass1(const float* __restrict__ U, const float* __restrict__ XD,
                const float* __restrict__ A_log,
                const float* __restrict__ dtw, const float* __restrict__ dtb,
                float* __restrict__ Pbuf, float* __restrict__ Sbuf)
{
    int idx = blockIdx.x * 256 + threadIdx.x;   // 262144
    int nh = idx & 1;
    int d  = (idx >> 1) & 511;
    int c  = (idx >> 10) & (SCAN_NC - 1);
    int b  = idx >> 15;

    float A[8], dw[16];
    #pragma unroll
    for (int g = 0; g < 2; ++g)
        *(float4*)&A[g * 4] = *(const float4*)(A_log + d * 16 + nh * 8 + g * 4);
    #pragma unroll
    for (int g = 0; g < 4; ++g)
        *(float4*)&dw[g * 4] = *(const float4*)(dtw + d * 16 + g * 4);
    #pragma unroll
    for (int n = 0; n < 8; ++n) A[n] = -__expf(A[n]);
    float db = dtb[d];

    float P[8], S[8];
    #pragma unroll
    for (int n = 0; n < 8; ++n) { P[n] = 1.f; S[n] = 0.f; }

    const float* uu = U  + ((size_t)b * 1024 + c * SCAN_TC) * 512 + d;
    const float* xd = XD + (size_t)b * 1024 * 48 + (size_t)(c * SCAN_TC) * 48;

    for (int tt = 0; tt < SCAN_TC; ++tt) {
        float dt[16];
        #pragma unroll
        for (int g = 0; g < 4; ++g)
            *(float4*)&dt[g * 4] = *(const float4*)(xd + tt * 48 + g * 4);
        float dl = db;
        #pragma unroll
        for (int k = 0; k < 16; ++k) dl += dt[k] * dw[k];
        float delta = softplus_fast(dl);
        float u = uu[(size_t)tt * 512];
        float du = delta * u;
        float Bm[8];
        #pragma unroll
        for (int g = 0; g < 2; ++g)
            *(float4*)&Bm[g * 4] = *(const float4*)(xd + tt * 48 + 16 + nh * 8 + g * 4);
        #pragma unroll
        for (int n = 0; n < 8; ++n) {
            float a = __expf(delta * A[n]);
            S[n] = a * S[n] + du * Bm[n];
            P[n] *= a;
        }
    }

    size_t off = ((size_t)(idx >> 1)) * 16 + nh * 8;
    #pragma unroll
    for (int g = 0; g < 2; ++g) {
        *(float4*)(Pbuf + off + g * 4) = *(const float4*)&P[g * 4];
        *(float4*)(Sbuf + off + g * 4) = *(const float4*)&S[g * 4];
    }
}

__global__ __launch_bounds__(256)
void scan_pass2(const float* __restrict__ Pbuf, float* __restrict__ Sbuf)
{
    int idx = blockIdx.x * 256 + threadIdx.x;   // 65536
    int dn = idx & 8191;
    int b  = idx >> 13;

    float h = 0.f;
    #pragma unroll 4
    for (int c = 0; c < SCAN_NC; ++c) {
        size_t off = (((size_t)b * SCAN_NC + c) * 512 * 16) + dn;
        float p = Pbuf[off];
        float s = Sbuf[off];
        Sbuf[off] = h;
        h = p * h + s;
    }
}

// pass3: replay from h_in; y reduced across the lane pair (shfl_xor 1);
// epilogue (y + u*Dp)*silu(z) -> Yb bf16 in the dead u-half of XZ.
__global__ __launch_bounds__(256)
void scan_pass3(const float* __restrict__ U, const float* __restrict__ XD,
                float* __restrict__ XZ,
                const float* __restrict__ A_log,
                const float* __restrict__ dtw, const float* __restrict__ dtb,
                const float* __restrict__ Dp, const float* __restrict__ Sbuf)
{
    int idx = blockIdx.x * 256 + threadIdx.x;   // 262144
    int nh = idx & 1;
    int d  = (idx >> 1) & 511;
    int c  = (idx >> 10) & (SCAN_NC - 1);
    int b  = idx >> 15;

    float A[8], dw[16], h[8];
    #pragma unroll
    for (int g = 0; g < 2; ++g)
        *(float4*)&A[g * 4] = *(const float4*)(A_log + d * 16 + nh * 8 + g * 4);
    #pragma unroll
    for (int g = 0; g < 4; ++g)
        *(float4*)&dw[g * 4] = *(const float4*)(dtw + d * 16 + g * 4);
    #pragma unroll
    for (int n = 0; n < 8; ++n) A[n] = -__expf(A[n]);
    float db = dtb[d];

    size_t soff = ((size_t)(idx >> 1)) * 16 + nh * 8;
    #pragma unroll
    for (int g = 0; g < 2; ++g)
        *(float4*)&h[g * 4] = *(const float4*)(Sbuf + soff + g * 4);

    float Dval = Dp[d];

    const float* uu = U  + ((size_t)b * 1024 + c * SCAN_TC) * 512 + d;
    const float* xd = XD + (size_t)b * 1024 * 48 + (size_t)(c * SCAN_TC) * 48;
    float* xz = XZ + ((size_t)b * 1024 + c * SCAN_TC) * 1024 + d;
    unsigned short* yb = (unsigned short*)(XZ) +
                         ((size_t)b * 1024 + c * SCAN_TC) * 2048 + d;

    for (int tt = 0; tt < SCAN_TC; ++tt) {
        float dt[16];
        #pragma unroll
        for (int g = 0; g < 4; ++g)
            *(float4*)&dt[g * 4] = *(const float4*)(xd + tt * 48 + g * 4);
        float dl = db;
        #pragma unroll
        for (int k = 0; k < 16; ++k) dl += dt[k] * dw[k];
        float delta = softplus_fast(dl);
        float u = uu[(size_t)tt * 512];
        float du = delta * u;
        float Bm[8], Cm[8];
        #pragma unroll
        for (int g = 0; g < 2; ++g) {
            *(float4*)&Bm[g * 4] = *(const float4*)(xd + tt * 48 + 16 + nh * 8 + g * 4);
            *(float4*)&Cm[g * 4] = *(const float4*)(xd + tt * 48 + 32 + nh * 8 + g * 4);
        }
        float y = 0.f;
        #pragma unroll
        for (int n = 0; n < 8; ++n) {
            float a = __expf(delta * A[n]);
            h[n] = a * h[n] + du * Bm[n];
            y += h[n] * Cm[n];
        }
        y += __shfl_xor(y, 1);   // lane pair = (d, nh=0/1)
        if (nh == 0) {
            float z = xz[(size_t)tt * 1024 + 512];
            float out = (y + u * Dval) * (z / (1.f + __expf(-z)));
            yb[(size_t)tt * 2048] = f2bfu(out);
        }
    }
}

// ---------------------------------------------------------------------------
extern "C" void kernel_launch(void* const* d_in, const int* in_sizes, int n_in,
                              void* d_out, int out_size, void* d_ws, size_t ws_size,
                              hipStream_t stream)
{
    (void)in_sizes; (void)n_in; (void)out_size; (void)ws_size;
    const float* sam   = (const float*)d_in[0];
    const float* myn   = (const float*)d_in[1];
    const float* wq    = (const float*)d_in[2];
    const float* bq    = (const float*)d_in[3];
    const float* wk    = (const float*)d_in[4];
    const float* bk    = (const float*)d_in[5];
    const float* wv    = (const float*)d_in[6];
    const float* bv    = (const float*)d_in[7];
    const float* wo    = (const float*)d_in[8];
    const float* bo    = (const float*)d_in[9];
    const float* cqw   = (const float*)d_in[10];
    const float* cqb   = (const float*)d_in[11];
    const float* ckw   = (const float*)d_in[12];
    const float* ckb   = (const float*)d_in[13];
    const float* cvw   = (const float*)d_in[14];
    const float* cvb   = (const float*)d_in[15];
    const float* gamma = (const float*)d_in[16];
    const float* to_seq_w   = (const float*)d_in[17];
    const float* to_seq_b   = (const float*)d_in[18];
    const float* in_proj_w  = (const float*)d_in[19];
    const float* conv_w     = (const float*)d_in[20];
    const float* conv_b     = (const float*)d_in[21];
    const float* x_proj_w   = (const float*)d_in[22];
    const float* dt_w       = (const float*)d_in[23];
    const float* dt_b       = (const float*)d_in[24];
    const float* A_log      = (const float*)d_in[25];
    const float* Dp         = (const float*)d_in[26];
    const float* out_proj_w = (const float*)d_in[27];
    const float* from_seq_w = (const float*)d_in[28];
    const float* from_seq_b = (const float*)d_in[29];

    // ---- workspace segments (floats), total 21,364,736 (~85.5 MB, proven) --
    float* wsf = (float*)d_ws;
    float* SEG_A = wsf;                          // 2,097,152  P0 fp32 / Pbuf d0
    float* SEG_B = wsf + (size_t)2097152;        // 2,097,152  P1 fp32 / Pbuf d1
    float* SEG_C = wsf + (size_t)4194304;        // 8,388,608  attn bf16 / QC,KC / XZ
    float* SEG_D = wsf + (size_t)12582912;       // 4,194,304  P0b,P1b / OH,VC / U
    float* SEG_E = wsf + (size_t)16777216;       // 4,194,304  Wb / Tb,MOb / Snb
    float* SEG_F = wsf + (size_t)20971520;       //   393,216  XD

    // bf16 views
    unsigned short* Wb   = (unsigned short*)SEG_E;              // 1,376,256
    unsigned short* TMb  = (unsigned short*)SEG_E + 1376256;    // 2,097,152 (Tb/MOb)
    unsigned short* Snb  = (unsigned short*)SEG_E + 3473408;    // 2,097,152 (Sinb/Soutb)
    unsigned short* Qbf  = (unsigned short*)SEG_C;              // 2,097,152
    unsigned short* Kbf  = (unsigned short*)SEG_C + 2097152;
    unsigned short* Vbf  = (unsigned short*)SEG_C + 4194304;
    unsigned short* Obf  = (unsigned short*)SEG_C + 6291456;
    unsigned short* P0b  = (unsigned short*)SEG_D;              // 2,097,152
    unsigned short* P1b  = (unsigned short*)SEG_D + 2097152;
    unsigned short* VTb  = (unsigned short*)d_out;              // 2,097,152
    float* P0 = SEG_A;
    float* P1 = SEG_B;
    float* QC = SEG_C;                     // 524,288 floats
    float* KC = SEG_C + 524288;
    float* OH = SEG_D;                     // 2,097,152 floats
    float* VC = SEG_D + 2097152;           // 2,097,152 floats
    float* OV = (float*)d_out;             // 2,097,152 floats (VT dead)
    float* XZ = SEG_C;                     // 8,388,608 floats
    float* Ub = SEG_D;                     // 4,194,304 floats
    float* XD = SEG_F;

    // Wb chunk offsets (shorts)
    const size_t WB_WQ = 0, WB_WK = 65536, WB_WV = 131072, WB_WO = 196608,
                 WB_CV = 262144, WB_D0 = 327680, WB_DSTRIDE = 524288;
    const size_t WB_TOSEQ = 0, WB_INPROJ = 65536, WB_OUTPROJ = 327680,
                 WB_FROMSEQ = 458752;

    // ---- weight pre-pack (21 x 65536) ----
    PackTab tab;
    tab.src[0] = wq; tab.src[1] = wk; tab.src[2] = wv; tab.src[3] = wo;
    tab.src[4] = cvw;
    for (int i = 0; i < 2; ++i) {
        int base = 5 + i * 8;
        tab.src[base + 0] = to_seq_w + (size_t)i * 65536;
        for (int c = 0; c < 4; ++c)
            tab.src[base + 1 + c] = in_proj_w + (size_t)i * 262144 + (size_t)c * 65536;
        for (int c = 0; c < 2; ++c)
            tab.src[base + 5 + c] = out_proj_w + (size_t)i * 131072 + (size_t)c * 65536;
        tab.src[base + 7] = from_seq_w + (size_t)i * 65536;
    }
    pack_weights_kernel<<<1344, 256, 0, stream>>>(tab, Wb);

    dim3 tb(32, 8, 1);
    // inputs (B,C,L) -> (B,L,C) bf16 only
    transpose_kernel<<<dim3(32, 8, 8), tb, 0, stream>>>(sam, nullptr, P0b, 256, 1024);
    transpose_kernel<<<dim3(32, 8, 8), tb, 0, stream>>>(myn, nullptr, P1b, 256, 1024);

    auto gemmMid = [&](const unsigned short* A, int lda, const unsigned short* W,
                       const float* bias, float* C, unsigned short* Cb, int N, int K) {
        gemm_bf16_kernel<2><<<dim3(N / 64, 128), 256, 0, stream>>>(
            A, lda, W, bias, C, Cb, N, K);
    };
    auto gemmWide = [&](const unsigned short* A, int lda, const unsigned short* W,
                        const float* bias, float* C, unsigned short* Cb, int N, int K) {
        gemm_bf16_kernel<4><<<dim3(N / 64, 64), 256, 0, stream>>>(
            A, lda, W, bias, C, Cb, N, K);
    };
    // fp32 linear, N <= 64, BM=32 -> 256 blocks
    auto linSmall = [&](const float* A, int lda, const float* W, const float* bias,
                        float* Cout, int N, int K, int act) {
        linear_kernel<32, 64, 2, 4><<<dim3(1, 256), 256, 0, stream>>>(
            A, lda, W, bias, Cout, 8192, N, K, act);
    };

    // ---- cross attention ----
    gemmMid(P0b, 256, Wb + WB_WQ, bq, nullptr, Qbf, 256, 256);
    gemmMid(P1b, 256, Wb + WB_WK, bk, nullptr, Kbf, 256, 256);
    gemmMid(P1b, 256, Wb + WB_WV, bv, nullptr, Vbf, 256, 256);
    pack_vt_kernel<<<dim3(32, 2, 32), tb, 0, stream>>>(Vbf, VTb);
    attn_mfma2_kernel<<<dim3(16, 4, 8), 256, 0, stream>>>(Qbf, Kbf, VTb, Obf);
    gemmMid(Obf, 256, Wb + WB_WO, bo, P0, P0b, 256, 256);   // fusion -> P0 (+bf16)

    // ---- criss-cross attention ----
    linSmall(P0, 256, cqw, cqb, QC, 64, 256, 0);
    linSmall(P0, 256, ckw, ckb, KC, 64, 256, 0);
    gemmMid (P0b, 256, Wb + WB_CV, cvb, VC, nullptr, 256, 256);
    cca_kernel<<<dim3(32, 8, 2), 256, 0, stream>>>(QC, KC, VC, OH, OV);
    combine_kernel<<<8192, 256, 0, stream>>>(OH, OV, P0, gamma, P1, Snb);

    // ---- 2x mamba blocks ----
    for (int i = 0; i < 2; ++i) {
        const unsigned short* Wd = Wb + WB_D0 + (size_t)i * WB_DSTRIDE;
        float* Sout = (i == 0) ? P0 : P1;

        gemmMid(Snb, 256, Wd + WB_TOSEQ, to_seq_b + i * 256, nullptr, TMb, 256, 256);
        gemmWide(TMb, 256, Wd + WB_INPROJ, nullptr, XZ, nullptr, 1024, 256);
        conv_silu_kernel<<<16384, 256, 0, stream>>>(XZ, conv_w + (size_t)i * 2048,
                                                    conv_b + i * 512, Ub);
        linSmall(Ub, 512, x_proj_w + (size_t)i * 24576, nullptr, XD, 48, 512, 0);

        float* Pbuf = Sout;
        float* Sbuf = (float*)d_out;
        scan_pass1<<<1024, 256, 0, stream>>>(Ub, XD, A_log + (size_t)i * 8192,
                                             dt_w + (size_t)i * 8192, dt_b + i * 512,
                                             Pbuf, Sbuf);
        scan_pass2<<<256, 256, 0, stream>>>(Pbuf, Sbuf);
        scan_pass3<<<1024, 256, 0, stream>>>(Ub, XD, XZ,
                                             A_log + (size_t)i * 8192,
                                             dt_w + (size_t)i * 8192, dt_b + i * 512,
                                             Dp + i * 512, Sbuf);

        // out_proj: A = Yb (bf16 in XZ u-half), lda 2048 ushorts
        gemmMid((const unsigned short*)XZ, 2048, Wd + WB_OUTPROJ, nullptr,
                nullptr, TMb, 256, 512);
        gemmMid(TMb, 256, Wd + WB_FROMSEQ, from_seq_b + i * 256, Sout, Snb, 256, 256);
    }

    // final (B,L,C) -> (B,C,L)
    transpose_kernel<<<dim3(8, 32, 8), tb, 0, stream>>>(P1, (float*)d_out, nullptr,
                                                        1024, 256);
}